// Round 4
// baseline (786.447 us; speedup 1.0000x reference)
//
#include <hip/hip_runtime.h>

#define NB 32
#define NP 24564
#define NOBJ 50
#define NC1 20          // NUM_CLASSES - 1
#define WTHRESH 0.5f

typedef unsigned long long u64;
typedef unsigned int u32;

// monotone float->uint mapping (works for all floats; our ranked values are >= 0)
__device__ __forceinline__ u32 f2s(float f){
  u32 u = __float_as_uint(f);
  return (u & 0x80000000u) ? ~u : (u | 0x80000000u);
}

// ---------------- init ----------------
__global__ __launch_bounds__(256) void k_init(int* ovr, u64* bpKey, int* numPos, double* acc){
  int i = blockIdx.x*256 + threadIdx.x;
  if (i < NB*NP)   ovr[i] = -1;
  if (i < NB*NOBJ) bpKey[i] = 0ull;
  if (i < NB)      numPos[i] = 0;
  if (i < 4)       acc[i] = 0.0;
}

// ---------------- match: IOU, best-truth per prior, best-prior per truth ----------------
__global__ __launch_bounds__(256) void k_match(const float* __restrict__ priors,
    const float* __restrict__ targets, float* __restrict__ ovArr,
    int* __restrict__ btIdx, u64* __restrict__ bpKey){
  const int b = blockIdx.y;
  const int j = blockIdx.x*256 + threadIdx.x;
  __shared__ float tr[NOBJ*5];
  if (threadIdx.x < NOBJ*5) tr[threadIdx.x] = targets[b*NOBJ*5 + threadIdx.x];
  __syncthreads();
  const bool valid = (j < NP);
  const int waveBase = blockIdx.x*256 + (threadIdx.x & ~63);
  float px1=0.f,py1=0.f,px2=0.f,py2=0.f, areaB=0.f;
  if (valid){
    float4 pr = reinterpret_cast<const float4*>(priors)[j];
    px1 = pr.x - pr.z*0.5f; py1 = pr.y - pr.w*0.5f;
    px2 = pr.x + pr.z*0.5f; py2 = pr.y + pr.w*0.5f;
    areaB = (px2-px1)*(py2-py1);
  }
  float bestOv = -1.0f; int bestT = 0;
  for (int t=0; t<NOBJ; t++){
    float iou = 0.0f;
    if (valid){
      float tx1=tr[t*5+0], ty1=tr[t*5+1], tx2=tr[t*5+2], ty2=tr[t*5+3];
      float w = fmaxf(fminf(tx2,px2)-fmaxf(tx1,px1), 0.f);
      float h = fmaxf(fminf(ty2,py2)-fmaxf(ty1,py1), 0.f);
      float inter = w*h;
      float areaA = (tx2-tx1)*(ty2-ty1);
      iou = inter / (areaA + areaB - inter);
      if (iou > bestOv){ bestOv = iou; bestT = t; }   // strict > == first occurrence (axis=0 argmax)
    }
    // per-truth argmax over priors; tie -> smallest j (JAX first occurrence).
    u32 key = valid ? f2s(iou) : 0u;
    u32 m = key;
    #pragma unroll
    for (int off=32; off>0; off>>=1){
      u32 o = __shfl_down(m, off);
      m = (o > m) ? o : m;
    }
    u32 kmax = __shfl(m, 0);
    u64 ball = __ballot(key == kmax);
    if ((threadIdx.x & 63) == 0 && kmax != 0u){
      int lane = __ffsll((unsigned long long)ball) - 1;
      u32 jwin = (u32)(waveBase + lane);
      u64 k64 = (((u64)kmax) << 32) | (u64)(~jwin);
      atomicMax(&bpKey[b*NOBJ + t], k64);
    }
  }
  if (valid){
    ovArr[(size_t)b*NP + j] = bestOv;
    btIdx[(size_t)b*NP + j] = bestT;
  }
}

// ---------------- scatter: force each truth's best prior ----------------
__global__ __launch_bounds__(256) void k_scatter(const u64* __restrict__ bpKey,
    float* __restrict__ ovArr, int* __restrict__ ovr){
  int i = blockIdx.x*256 + threadIdx.x;
  if (i >= NB*NOBJ) return;
  int b = i / NOBJ;
  int t = i % NOBJ;
  u64 key = bpKey[i];
  int j = (int)(~(u32)key);
  ovArr[(size_t)b*NP + j] = 2.0f;                 // .at[best_prior_idx].set(2.0)
  atomicMax(&ovr[(size_t)b*NP + j], t);           // .at[best_prior_idx].max(arange)
}

// ---------------- per-prior losses + pos mask + pos-side sums ----------------
// ceBinOut aliases ovArr, ceMulOut aliases btIdx (read-before-write per thread) -> no __restrict__.
// NO local arrays anywhere: five named float4s, fully hand-unrolled straight-line code.
// Sum accumulation order kept identical to the previously-passing version (bit-repro).
__global__ __launch_bounds__(256) void k_loss(
    const float* loc, const float* conf, const float* binc,
    const float* priors, const float* targets,
    const float* ovArr, const int* btIdx, const int* ovr,
    float* ceBinOut, float* ceMulOut, float* posOut, int* numPos, double* acc){
  const int b = blockIdx.y;
  const int j = blockIdx.x*256 + threadIdx.x;
  __shared__ float tr[NOBJ*5];
  if (threadIdx.x < NOBJ*5) tr[threadIdx.x] = targets[b*NOBJ*5 + threadIdx.x];
  __syncthreads();
  float sl1=0.f, ceB=0.f, ceM=0.f; int isPos=0;
  if (j < NP){
    const size_t idx = (size_t)b*NP + j;
    // issue all independent global loads up front
    float4 ld = reinterpret_cast<const float4*>(loc)[idx];
    float2 bc = reinterpret_cast<const float2*>(binc)[idx];
    float4 pr = reinterpret_cast<const float4*>(priors)[j];
    const float4* cp = reinterpret_cast<const float4*>(conf + idx*NC1);
    float4 c0 = cp[0];
    float4 c1 = cp[1];
    float4 c2 = cp[2];
    float4 c3 = cp[3];
    float4 c4 = cp[4];
    float ov = ovArr[idx];
    int o  = ovr[idx];
    int bt = btIdx[idx];
    int ti = (o >= 0) ? o : bt;
    float tx1=tr[ti*5+0], ty1=tr[ti*5+1], tx2=tr[ti*5+2], ty2=tr[ti*5+3], lab=tr[ti*5+4];
    int conf_t = (ov < WTHRESH) ? 0 : ((int)lab + 1);
    isPos = (conf_t > 0) ? 1 : 0;
    // encode + smooth L1
    float gcx = ((tx1+tx2)*0.5f - pr.x) / (0.1f*pr.z);
    float gcy = ((ty1+ty2)*0.5f - pr.y) / (0.1f*pr.w);
    float gw  = logf((tx2-tx1)/pr.z) / 0.2f;
    float gh  = logf((ty2-ty1)/pr.w) / 0.2f;
    float d0=fabsf(ld.x-gcx), d1=fabsf(ld.y-gcy), d2=fabsf(ld.z-gw), d3=fabsf(ld.w-gh);
    sl1  = (d0<1.f ? 0.5f*d0*d0 : d0-0.5f);
    sl1 += (d1<1.f ? 0.5f*d1*d1 : d1-0.5f);
    sl1 += (d2<1.f ? 0.5f*d2*d2 : d2-0.5f);
    sl1 += (d3<1.f ? 0.5f*d3*d3 : d3-0.5f);
    // binary CE
    float mB = fmaxf(bc.x, bc.y);
    float lseB = logf(expf(bc.x-mB)+expf(bc.y-mB)) + mB;
    ceB = lseB - (isPos ? bc.y : bc.x);
    // max over 20 conf logits (max is order-independent -> tree is bit-safe)
    float mc = fmaxf(fmaxf(fmaxf(c0.x,c0.y),fmaxf(c0.z,c0.w)),
                     fmaxf(fmaxf(c1.x,c1.y),fmaxf(c1.z,c1.w)));
    mc = fmaxf(mc, fmaxf(fmaxf(c2.x,c2.y),fmaxf(c2.z,c2.w)));
    mc = fmaxf(mc, fmaxf(fmaxf(c3.x,c3.y),fmaxf(c3.z,c3.w)));
    mc = fmaxf(mc, fmaxf(fmaxf(c4.x,c4.y),fmaxf(c4.z,c4.w)));
    // lse(conf): sequential ascending accumulation (same order as before)
    float se = expf(c0.x-mc); se += expf(c0.y-mc); se += expf(c0.z-mc); se += expf(c0.w-mc);
    se += expf(c1.x-mc); se += expf(c1.y-mc); se += expf(c1.z-mc); se += expf(c1.w-mc);
    se += expf(c2.x-mc); se += expf(c2.y-mc); se += expf(c2.z-mc); se += expf(c2.w-mc);
    se += expf(c3.x-mc); se += expf(c3.y-mc); se += expf(c3.z-mc); se += expf(c3.w-mc);
    se += expf(c4.x-mc); se += expf(c4.y-mc); se += expf(c4.z-mc); se += expf(c4.w-mc);
    float lseC = logf(se) + mc;
    float P0 = bc.x + lseC;
    // lse over P_logit = [P0, conf + bin1]: same per-element form & order as before
    float m2 = fmaxf(P0, mc + bc.y);
    float s2 = expf(P0 - m2);
    s2 += expf(c0.x + bc.y - m2); s2 += expf(c0.y + bc.y - m2); s2 += expf(c0.z + bc.y - m2); s2 += expf(c0.w + bc.y - m2);
    s2 += expf(c1.x + bc.y - m2); s2 += expf(c1.y + bc.y - m2); s2 += expf(c1.z + bc.y - m2); s2 += expf(c1.w + bc.y - m2);
    s2 += expf(c2.x + bc.y - m2); s2 += expf(c2.y + bc.y - m2); s2 += expf(c2.z + bc.y - m2); s2 += expf(c2.w + bc.y - m2);
    s2 += expf(c3.x + bc.y - m2); s2 += expf(c3.y + bc.y - m2); s2 += expf(c3.z + bc.y - m2); s2 += expf(c3.w + bc.y - m2);
    s2 += expf(c4.x + bc.y - m2); s2 += expf(c4.y + bc.y - m2); s2 += expf(c4.z + bc.y - m2); s2 += expf(c4.w + bc.y - m2);
    float lseM = logf(s2) + m2;
    // pick conf[sel] with a cndmask chain (no array, no dynamic index)
    int sel = conf_t - 1;
    float csel = c0.x;
    csel = (sel== 1) ? c0.y : csel;
    csel = (sel== 2) ? c0.z : csel;
    csel = (sel== 3) ? c0.w : csel;
    csel = (sel== 4) ? c1.x : csel;
    csel = (sel== 5) ? c1.y : csel;
    csel = (sel== 6) ? c1.z : csel;
    csel = (sel== 7) ? c1.w : csel;
    csel = (sel== 8) ? c2.x : csel;
    csel = (sel== 9) ? c2.y : csel;
    csel = (sel==10) ? c2.z : csel;
    csel = (sel==11) ? c2.w : csel;
    csel = (sel==12) ? c3.x : csel;
    csel = (sel==13) ? c3.y : csel;
    csel = (sel==14) ? c3.z : csel;
    csel = (sel==15) ? c3.w : csel;
    csel = (sel==16) ? c4.x : csel;
    csel = (sel==17) ? c4.y : csel;
    csel = (sel==18) ? c4.z : csel;
    csel = (sel==19) ? c4.w : csel;
    float g = (conf_t==0) ? P0 : (csel + bc.y);
    ceM = lseM - g;
    ceBinOut[idx] = isPos ? 0.f : ceB;
    ceMulOut[idx] = isPos ? 0.f : ceM;
    posOut[idx]   = isPos ? 1.f : 0.f;
  }
  float a0 = isPos ? sl1 : 0.f;
  float a1 = isPos ? ceM : 0.f;
  float a2 = isPos ? ceB : 0.f;
  int cnt = isPos;
  #pragma unroll
  for (int off=32; off>0; off>>=1){
    a0 += __shfl_down(a0, off);
    a1 += __shfl_down(a1, off);
    a2 += __shfl_down(a2, off);
    cnt += __shfl_down(cnt, off);
  }
  if ((threadIdx.x & 63) == 0){
    if (cnt)        atomicAdd(&numPos[b], cnt);
    if (a0 != 0.f)  atomicAdd(&acc[0], (double)a0);
    if (a1 != 0.f)  atomicAdd(&acc[1], (double)a1);
    if (a2 != 0.f)  atomicAdd(&acc[2], (double)a2);
  }
}

// ---------------- exact top-k selection per row (stable-argsort semantics) ----------------
// 1024 threads/block (16 waves) for latency hiding; parallel suffix-scan bin selection.
__global__ __launch_bounds__(1024) void k_rank(const float* __restrict__ ceBin,
    const float* __restrict__ ceMul, const int* __restrict__ numPos,
    float* __restrict__ negBinOut, float* __restrict__ negMulOut, double* acc){
  const int b = blockIdx.x;
  const int which = blockIdx.y;        // 0 = binary loss, 1 = multiclass loss
  const float* arr = (which==0 ? ceBin : ceMul) + (size_t)b*NP;
  float* out = (which==0 ? negBinOut : negMulOut) + (size_t)b*NP;
  const int tid = threadIdx.x;
  int np = numPos[b];
  int k = min(3*np, NP-1);
  if (k <= 0){
    for (int i=tid; i<NP; i+=1024) out[i] = 0.f;
    return;
  }
  __shared__ u32 hist[256];
  __shared__ u32 scan[256];
  __shared__ u32 s_pref;
  __shared__ int s_rem;
  if (tid==0){ s_pref = 0u; s_rem = k; }
  if (tid < 256) hist[tid] = 0u;
  __syncthreads();
  for (int r=0; r<4; r++){
    u32 pref = s_pref;
    int sh = 24 - 8*r;
    for (int i=tid; i<NP; i+=1024){
      u32 s = f2s(arr[i]);
      if (r==0 || (s >> (sh+8)) == (pref >> (sh+8)))
        atomicAdd(&hist[(s >> sh) & 255u], 1u);
    }
    __syncthreads();
    // suffix-sum from the top: scan[bin] = # elements with digit >= bin (within prefix group)
    if (tid < 256) scan[tid] = hist[tid];
    __syncthreads();
    for (int st=1; st<256; st<<=1){
      u32 add = 0u;
      if (tid < 256 && tid + st < 256) add = scan[tid + st];
      __syncthreads();
      if (tid < 256) scan[tid] += add;
      __syncthreads();
    }
    if (tid < 256){
      u32 rem = (u32)s_rem;
      u32 inclusive = scan[tid];
      u32 above = (tid < 255) ? scan[tid+1] : 0u;
      if (inclusive >= rem && above < rem){   // exactly one bin satisfies this
        s_pref = pref | ((u32)tid << sh);
        s_rem  = (int)(rem - above);
      }
      hist[tid] = 0u;   // reset for next pass
    }
    __syncthreads();
  }
  const u32 kth = s_pref;     // exact k-th largest key
  const int need = s_rem;     // how many of the ties (by smallest index) are selected
  __shared__ int eqCnt;
  __shared__ int eqIdx[2048];
  if (tid==0) eqCnt = 0;
  __syncthreads();
  float sum = 0.f;
  for (int i=tid; i<NP; i+=1024){
    float v = arr[i];
    u32 s = f2s(v);
    float o = 0.f;
    if (s > kth){ o = 1.f; sum += v; }
    else if (s == kth){ int p = atomicAdd(&eqCnt, 1); if (p < 2048) eqIdx[p] = i; }
    out[i] = o;
  }
  __syncthreads();
  int ec = min(eqCnt, 2048);
  for (int e=tid; e<ec; e+=1024){
    int idx = eqIdx[e]; int rank = 0;
    for (int f=0; f<ec; f++) rank += (eqIdx[f] < idx) ? 1 : 0;
    if (rank < need){ out[idx] = 1.f; sum += arr[idx]; }
  }
  if (which==0){
    #pragma unroll
    for (int off=32; off>0; off>>=1) sum += __shfl_down(sum, off);
    if ((tid & 63) == 0 && sum != 0.f) atomicAdd(&acc[3], (double)sum);
  }
}

// ---------------- finalize scalars ----------------
__global__ void k_final(const int* numPos, const double* acc, float* out){
  if (threadIdx.x==0 && blockIdx.x==0){
    int s = 0;
    for (int b=0; b<NB; b++) s += numPos[b];
    float N = fmaxf((float)s, 1.0f);
    out[0] = (float)(acc[0] / (double)N);                 // loss_l / N
    out[1] = (float)(acc[1] / (double)N);                 // loss_cls / N
    out[2] = (float)((acc[2] + 3.0*acc[3]) / (double)N);  // loss_b / N  (w_bin[0]=3 on negatives)
  }
}

extern "C" void kernel_launch(void* const* d_in, const int* in_sizes, int n_in,
                              void* d_out, int out_size, void* d_ws, size_t ws_size,
                              hipStream_t stream) {
  const float* loc     = (const float*)d_in[0];
  const float* conf    = (const float*)d_in[1];
  const float* binc    = (const float*)d_in[2];
  const float* priors  = (const float*)d_in[3];
  const float* targets = (const float*)d_in[4];
  float* out = (float*)d_out;

  char* ws = (char*)d_ws;
  float* ovArr  = (float*)ws;                                   // NB*NP f32 -> reused as ceBin
  int*   btIdx  = (int*)(ws + (size_t)NB*NP*4);                 // NB*NP i32 -> reused as ceMul
  int*   ovr    = (int*)(ws + (size_t)NB*NP*8);                 // NB*NP i32
  u64*   bpKey  = (u64*)(ws + (size_t)NB*NP*12);                // NB*NOBJ u64
  int*   numPos = (int*)(ws + (size_t)NB*NP*12 + NB*NOBJ*8);    // NB i32
  double* acc   = (double*)(ws + (size_t)NB*NP*12 + NB*NOBJ*8 + NB*4); // 4 f64

  float* posOut    = out + 3;
  float* negBinOut = out + 3 + (size_t)NB*NP;
  float* negMulOut = out + 3 + (size_t)2*NB*NP;

  const int pbBlocks = (NP + 255)/256;      // 96
  k_init<<<(NB*NP + 255)/256, 256, 0, stream>>>(ovr, bpKey, numPos, acc);
  k_match<<<dim3(pbBlocks, NB), 256, 0, stream>>>(priors, targets, ovArr, btIdx, bpKey);
  k_scatter<<<(NB*NOBJ + 255)/256, 256, 0, stream>>>(bpKey, ovArr, ovr);
  k_loss<<<dim3(pbBlocks, NB), 256, 0, stream>>>(loc, conf, binc, priors, targets,
      ovArr, btIdx, ovr, ovArr /*ceBin*/, (float*)btIdx /*ceMul*/, posOut, numPos, acc);
  k_rank<<<dim3(NB, 2), 1024, 0, stream>>>(ovArr, (const float*)btIdx, numPos,
      negBinOut, negMulOut, acc);
  k_final<<<1, 64, 0, stream>>>(numPos, acc, out);
}

// Round 6
// 240.694 us; speedup vs baseline: 3.2674x; 3.2674x over previous
//
#include <hip/hip_runtime.h>

#define NB 32
#define NP 24564
#define NOBJ 50
#define NC1 20          // NUM_CLASSES - 1
#define WTHRESH 0.5f
#define PB 96           // blocks per batch row = ceil(NP/256)

typedef unsigned long long u64;
typedef unsigned int u32;

// monotone float->uint mapping (works for all floats; our ranked values are >= 0)
__device__ __forceinline__ u32 f2s(float f){
  u32 u = __float_as_uint(f);
  return (u & 0x80000000u) ? ~u : (u | 0x80000000u);
}

// ---------------- init ----------------
__global__ __launch_bounds__(256) void k_init(int* ovr, double* acc){
  int i = blockIdx.x*256 + threadIdx.x;
  if (i < NB*NP) ovr[i] = -1;
  if (i < 4)     acc[i] = 0.0;
}

// ---------------- match: IOU, best-truth per prior, best-prior per truth ----------------
// NO global atomics: per-block winners go to bpPart[b][t][blk]; k_scatter max-reduces.
__global__ __launch_bounds__(256) void k_match(const float* __restrict__ priors,
    const float* __restrict__ targets, float* __restrict__ ovArr,
    int* __restrict__ btIdx, u64* __restrict__ bpPart){
  const int b = blockIdx.y;
  const int blk = blockIdx.x;
  const int j = blk*256 + threadIdx.x;
  __shared__ float tr[NOBJ*5];
  __shared__ u64 wkey[NOBJ*4];          // per-truth per-wave best key
  if (threadIdx.x < NOBJ*5) tr[threadIdx.x] = targets[b*NOBJ*5 + threadIdx.x];
  __syncthreads();
  const bool valid = (j < NP);
  const int wave = threadIdx.x >> 6;
  const int waveBase = blk*256 + (threadIdx.x & ~63);
  float px1=0.f,py1=0.f,px2=0.f,py2=0.f, areaB=0.f;
  if (valid){
    float4 pr = reinterpret_cast<const float4*>(priors)[j];
    px1 = pr.x - pr.z*0.5f; py1 = pr.y - pr.w*0.5f;
    px2 = pr.x + pr.z*0.5f; py2 = pr.y + pr.w*0.5f;
    areaB = (px2-px1)*(py2-py1);
  }
  float bestOv = -1.0f; int bestT = 0;
  for (int t=0; t<NOBJ; t++){
    float iou = 0.0f;
    if (valid){
      float tx1=tr[t*5+0], ty1=tr[t*5+1], tx2=tr[t*5+2], ty2=tr[t*5+3];
      float w = fmaxf(fminf(tx2,px2)-fmaxf(tx1,px1), 0.f);
      float h = fmaxf(fminf(ty2,py2)-fmaxf(ty1,py1), 0.f);
      float inter = w*h;
      float areaA = (tx2-tx1)*(ty2-ty1);
      iou = inter / (areaA + areaB - inter);
      if (iou > bestOv){ bestOv = iou; bestT = t; }   // strict > == first occurrence (axis=0 argmax)
    }
    // per-truth argmax over this wave; tie -> smallest j (JAX first occurrence).
    // invalid lanes get key 0; a max-lane always exists (ballot never empty).
    u32 key = valid ? f2s(iou) : 0u;
    u32 m = key;
    #pragma unroll
    for (int off=32; off>0; off>>=1){
      u32 o = __shfl_down(m, off);
      m = (o > m) ? o : m;
    }
    u32 kmax = __shfl(m, 0);
    u64 ball = __ballot(key == kmax);
    if ((threadIdx.x & 63) == 0){
      int lane = __ffsll((unsigned long long)ball) - 1;
      u32 jwin = (u32)(waveBase + lane);
      wkey[t*4 + wave] = (((u64)kmax) << 32) | (u64)(~jwin);
    }
  }
  if (valid){
    ovArr[(size_t)b*NP + j] = bestOv;
    btIdx[(size_t)b*NP + j] = bestT;
  }
  __syncthreads();
  if (threadIdx.x < NOBJ){
    int t = threadIdx.x;
    u64 k0 = wkey[t*4+0], k1 = wkey[t*4+1], k2 = wkey[t*4+2], k3 = wkey[t*4+3];
    u64 kk = k0 > k1 ? k0 : k1;
    u64 kl = k2 > k3 ? k2 : k3;
    kk = kk > kl ? kk : kl;
    bpPart[((size_t)b*NOBJ + t)*PB + blk] = kk;   // unconditional -> no init needed
  }
}

// ---------------- scatter: reduce per-block winners, force each truth's best prior ----------------
__global__ __launch_bounds__(256) void k_scatter(const u64* __restrict__ bpPart,
    float* __restrict__ ovArr, int* __restrict__ ovr){
  int i = blockIdx.x*256 + threadIdx.x;
  if (i >= NB*NOBJ) return;
  const u64* p = bpPart + (size_t)i*PB;
  u64 key = 0ull;
  for (int blk=0; blk<PB; blk++){ u64 v = p[blk]; key = v > key ? v : key; }
  int b = i / NOBJ;
  int t = i % NOBJ;
  int j = (int)(~(u32)key);
  ovArr[(size_t)b*NP + j] = 2.0f;                 // .at[best_prior_idx].set(2.0)
  atomicMax(&ovr[(size_t)b*NP + j], t);           // .at[best_prior_idx].max(arange) — 1600 scattered ops
}

// ---------------- per-prior losses + pos mask + per-block partial sums ----------------
// ceBinOut aliases ovArr, ceMulOut aliases btIdx (read-before-write per thread) -> no __restrict__.
// NO global atomics: per-block partials to a0P/a1P/a2P/posCnt.
__global__ __launch_bounds__(256) void k_loss(
    const float* loc, const float* conf, const float* binc,
    const float* priors, const float* targets,
    const float* ovArr, const int* btIdx, const int* ovr,
    float* ceBinOut, float* ceMulOut, float* posOut,
    float* a0P, float* a1P, float* a2P, int* posCnt){
  const int b = blockIdx.y;
  const int j = blockIdx.x*256 + threadIdx.x;
  __shared__ float tr[NOBJ*5];
  __shared__ float s0[4], s1[4], s2s[4];
  __shared__ int scnt[4];
  if (threadIdx.x < NOBJ*5) tr[threadIdx.x] = targets[b*NOBJ*5 + threadIdx.x];
  __syncthreads();
  float sl1=0.f, ceB=0.f, ceM=0.f; int isPos=0;
  if (j < NP){
    const size_t idx = (size_t)b*NP + j;
    float4 ld = reinterpret_cast<const float4*>(loc)[idx];
    float2 bc = reinterpret_cast<const float2*>(binc)[idx];
    float4 pr = reinterpret_cast<const float4*>(priors)[j];
    const float4* cp = reinterpret_cast<const float4*>(conf + idx*NC1);
    float4 c0 = cp[0];
    float4 c1 = cp[1];
    float4 c2 = cp[2];
    float4 c3 = cp[3];
    float4 c4 = cp[4];
    float ov = ovArr[idx];
    int o  = ovr[idx];
    int bt = btIdx[idx];
    int ti = (o >= 0) ? o : bt;
    float tx1=tr[ti*5+0], ty1=tr[ti*5+1], tx2=tr[ti*5+2], ty2=tr[ti*5+3], lab=tr[ti*5+4];
    int conf_t = (ov < WTHRESH) ? 0 : ((int)lab + 1);
    isPos = (conf_t > 0) ? 1 : 0;
    // encode + smooth L1
    float gcx = ((tx1+tx2)*0.5f - pr.x) / (0.1f*pr.z);
    float gcy = ((ty1+ty2)*0.5f - pr.y) / (0.1f*pr.w);
    float gw  = logf((tx2-tx1)/pr.z) / 0.2f;
    float gh  = logf((ty2-ty1)/pr.w) / 0.2f;
    float d0=fabsf(ld.x-gcx), d1=fabsf(ld.y-gcy), d2=fabsf(ld.z-gw), d3=fabsf(ld.w-gh);
    sl1  = (d0<1.f ? 0.5f*d0*d0 : d0-0.5f);
    sl1 += (d1<1.f ? 0.5f*d1*d1 : d1-0.5f);
    sl1 += (d2<1.f ? 0.5f*d2*d2 : d2-0.5f);
    sl1 += (d3<1.f ? 0.5f*d3*d3 : d3-0.5f);
    // binary CE
    float mB = fmaxf(bc.x, bc.y);
    float lseB = logf(expf(bc.x-mB)+expf(bc.y-mB)) + mB;
    ceB = lseB - (isPos ? bc.y : bc.x);
    // multiclass CE over P_logit = [bin0+lse(conf), conf+bin1]
    float mc = fmaxf(fmaxf(fmaxf(c0.x,c0.y),fmaxf(c0.z,c0.w)),
                     fmaxf(fmaxf(c1.x,c1.y),fmaxf(c1.z,c1.w)));
    mc = fmaxf(mc, fmaxf(fmaxf(c2.x,c2.y),fmaxf(c2.z,c2.w)));
    mc = fmaxf(mc, fmaxf(fmaxf(c3.x,c3.y),fmaxf(c3.z,c3.w)));
    mc = fmaxf(mc, fmaxf(fmaxf(c4.x,c4.y),fmaxf(c4.z,c4.w)));
    float se = expf(c0.x-mc); se += expf(c0.y-mc); se += expf(c0.z-mc); se += expf(c0.w-mc);
    se += expf(c1.x-mc); se += expf(c1.y-mc); se += expf(c1.z-mc); se += expf(c1.w-mc);
    se += expf(c2.x-mc); se += expf(c2.y-mc); se += expf(c2.z-mc); se += expf(c2.w-mc);
    se += expf(c3.x-mc); se += expf(c3.y-mc); se += expf(c3.z-mc); se += expf(c3.w-mc);
    se += expf(c4.x-mc); se += expf(c4.y-mc); se += expf(c4.z-mc); se += expf(c4.w-mc);
    float lseC = logf(se) + mc;
    float P0 = bc.x + lseC;
    float m2 = fmaxf(P0, mc + bc.y);
    float s2 = expf(P0 - m2);
    s2 += expf(c0.x + bc.y - m2); s2 += expf(c0.y + bc.y - m2); s2 += expf(c0.z + bc.y - m2); s2 += expf(c0.w + bc.y - m2);
    s2 += expf(c1.x + bc.y - m2); s2 += expf(c1.y + bc.y - m2); s2 += expf(c1.z + bc.y - m2); s2 += expf(c1.w + bc.y - m2);
    s2 += expf(c2.x + bc.y - m2); s2 += expf(c2.y + bc.y - m2); s2 += expf(c2.z + bc.y - m2); s2 += expf(c2.w + bc.y - m2);
    s2 += expf(c3.x + bc.y - m2); s2 += expf(c3.y + bc.y - m2); s2 += expf(c3.z + bc.y - m2); s2 += expf(c3.w + bc.y - m2);
    s2 += expf(c4.x + bc.y - m2); s2 += expf(c4.y + bc.y - m2); s2 += expf(c4.z + bc.y - m2); s2 += expf(c4.w + bc.y - m2);
    float lseM = logf(s2) + m2;
    int sel = conf_t - 1;
    float csel = c0.x;
    csel = (sel== 1) ? c0.y : csel;
    csel = (sel== 2) ? c0.z : csel;
    csel = (sel== 3) ? c0.w : csel;
    csel = (sel== 4) ? c1.x : csel;
    csel = (sel== 5) ? c1.y : csel;
    csel = (sel== 6) ? c1.z : csel;
    csel = (sel== 7) ? c1.w : csel;
    csel = (sel== 8) ? c2.x : csel;
    csel = (sel== 9) ? c2.y : csel;
    csel = (sel==10) ? c2.z : csel;
    csel = (sel==11) ? c2.w : csel;
    csel = (sel==12) ? c3.x : csel;
    csel = (sel==13) ? c3.y : csel;
    csel = (sel==14) ? c3.z : csel;
    csel = (sel==15) ? c3.w : csel;
    csel = (sel==16) ? c4.x : csel;
    csel = (sel==17) ? c4.y : csel;
    csel = (sel==18) ? c4.z : csel;
    csel = (sel==19) ? c4.w : csel;
    float g = (conf_t==0) ? P0 : (csel + bc.y);
    ceM = lseM - g;
    ceBinOut[idx] = isPos ? 0.f : ceB;
    ceMulOut[idx] = isPos ? 0.f : ceM;
    posOut[idx]   = isPos ? 1.f : 0.f;
  }
  // block-level reduction: wave shuffle -> LDS -> single partial write (NO atomics)
  float a0 = isPos ? sl1 : 0.f;
  float a1 = isPos ? ceM : 0.f;
  float a2 = isPos ? ceB : 0.f;
  int cnt = isPos;
  #pragma unroll
  for (int off=32; off>0; off>>=1){
    a0 += __shfl_down(a0, off);
    a1 += __shfl_down(a1, off);
    a2 += __shfl_down(a2, off);
    cnt += __shfl_down(cnt, off);
  }
  if ((threadIdx.x & 63) == 0){
    int w = threadIdx.x >> 6;
    s0[w]=a0; s1[w]=a1; s2s[w]=a2; scnt[w]=cnt;
  }
  __syncthreads();
  if (threadIdx.x == 0){
    int g = b*PB + blockIdx.x;
    a0P[g] = s0[0]+s0[1]+s0[2]+s0[3];
    a1P[g] = s1[0]+s1[1]+s1[2]+s1[3];
    a2P[g] = s2s[0]+s2s[1]+s2s[2]+s2s[3];
    posCnt[g] = scnt[0]+scnt[1]+scnt[2]+scnt[3];
  }
}

// ---------------- exact top-k selection per row (stable-argsort semantics) ----------------
__global__ __launch_bounds__(1024) void k_rank(const float* __restrict__ ceBin,
    const float* __restrict__ ceMul, const int* __restrict__ posCnt,
    float* __restrict__ negBinOut, float* __restrict__ negMulOut, double* acc){
  const int b = blockIdx.x;
  const int which = blockIdx.y;        // 0 = binary loss, 1 = multiclass loss
  const float* arr = (which==0 ? ceBin : ceMul) + (size_t)b*NP;
  float* out = (which==0 ? negBinOut : negMulOut) + (size_t)b*NP;
  const int tid = threadIdx.x;
  __shared__ int s_cnt[PB];
  __shared__ int s_np;
  if (tid < PB) s_cnt[tid] = posCnt[b*PB + tid];
  __syncthreads();
  if (tid == 0){
    int s = 0;
    for (int i=0;i<PB;i++) s += s_cnt[i];
    s_np = s;
  }
  __syncthreads();
  int np = s_np;
  int k = min(3*np, NP-1);
  if (k <= 0){
    for (int i=tid; i<NP; i+=1024) out[i] = 0.f;
    return;
  }
  __shared__ u32 hist[256];
  __shared__ u32 scan[256];
  __shared__ u32 s_pref;
  __shared__ int s_rem;
  if (tid==0){ s_pref = 0u; s_rem = k; }
  if (tid < 256) hist[tid] = 0u;
  __syncthreads();
  for (int r=0; r<4; r++){
    u32 pref = s_pref;
    int sh = 24 - 8*r;
    for (int i=tid; i<NP; i+=1024){
      u32 s = f2s(arr[i]);
      if (r==0 || (s >> (sh+8)) == (pref >> (sh+8)))
        atomicAdd(&hist[(s >> sh) & 255u], 1u);
    }
    __syncthreads();
    if (tid < 256) scan[tid] = hist[tid];
    __syncthreads();
    for (int st=1; st<256; st<<=1){
      u32 add = 0u;
      if (tid < 256 && tid + st < 256) add = scan[tid + st];
      __syncthreads();
      if (tid < 256) scan[tid] += add;
      __syncthreads();
    }
    if (tid < 256){
      u32 rem = (u32)s_rem;
      u32 inclusive = scan[tid];
      u32 above = (tid < 255) ? scan[tid+1] : 0u;
      if (inclusive >= rem && above < rem){   // exactly one bin satisfies this
        s_pref = pref | ((u32)tid << sh);
        s_rem  = (int)(rem - above);
      }
      hist[tid] = 0u;   // reset for next pass
    }
    __syncthreads();
  }
  const u32 kth = s_pref;     // exact k-th largest key
  const int need = s_rem;     // how many of the ties (by smallest index) are selected
  __shared__ int eqCnt;
  __shared__ int eqIdx[2048];
  if (tid==0) eqCnt = 0;
  __syncthreads();
  float sum = 0.f;
  for (int i=tid; i<NP; i+=1024){
    float v = arr[i];
    u32 s = f2s(v);
    float o = 0.f;
    if (s > kth){ o = 1.f; sum += v; }
    else if (s == kth){ int p = atomicAdd(&eqCnt, 1); if (p < 2048) eqIdx[p] = i; }
    out[i] = o;
  }
  __syncthreads();
  int ec = min(eqCnt, 2048);
  for (int e=tid; e<ec; e+=1024){
    int idx = eqIdx[e]; int rank = 0;
    for (int f=0; f<ec; f++) rank += (eqIdx[f] < idx) ? 1 : 0;
    if (rank < need){ out[idx] = 1.f; sum += arr[idx]; }
  }
  if (which==0){
    // block-reduce, ONE atomic per block (32 total across grid)
    __shared__ float s_sum[16];
    #pragma unroll
    for (int off=32; off>0; off>>=1) sum += __shfl_down(sum, off);
    if ((tid & 63) == 0) s_sum[tid >> 6] = sum;
    __syncthreads();
    if (tid == 0){
      float t = 0.f;
      for (int w=0; w<16; w++) t += s_sum[w];
      if (t != 0.f) atomicAdd(&acc[3], (double)t);
    }
  }
}

// ---------------- finalize scalars ----------------
__global__ __launch_bounds__(256) void k_final(const float* __restrict__ a0P,
    const float* __restrict__ a1P, const float* __restrict__ a2P,
    const int* __restrict__ posCnt, const double* __restrict__ acc, float* out){
  const int tid = threadIdx.x;
  double a0=0.0, a1=0.0, a2=0.0; int cnt=0;
  for (int g=tid; g<NB*PB; g+=256){
    a0 += (double)a0P[g];
    a1 += (double)a1P[g];
    a2 += (double)a2P[g];
    cnt += posCnt[g];
  }
  #pragma unroll
  for (int off=32; off>0; off>>=1){
    a0 += __shfl_down(a0, off);
    a1 += __shfl_down(a1, off);
    a2 += __shfl_down(a2, off);
    cnt += __shfl_down(cnt, off);
  }
  __shared__ double sa0[4], sa1[4], sa2[4];
  __shared__ int scn[4];
  if ((tid & 63) == 0){ int w=tid>>6; sa0[w]=a0; sa1[w]=a1; sa2[w]=a2; scn[w]=cnt; }
  __syncthreads();
  if (tid == 0){
    double t0=sa0[0]+sa0[1]+sa0[2]+sa0[3];
    double t1=sa1[0]+sa1[1]+sa1[2]+sa1[3];
    double t2=sa2[0]+sa2[1]+sa2[2]+sa2[3];
    int s = scn[0]+scn[1]+scn[2]+scn[3];
    double N = (double)max(s, 1);
    out[0] = (float)(t0 / N);                 // loss_l / N
    out[1] = (float)(t1 / N);                 // loss_cls / N
    out[2] = (float)((t2 + 3.0*acc[3]) / N);  // loss_b / N  (w_bin[0]=3 on negatives)
  }
}

extern "C" void kernel_launch(void* const* d_in, const int* in_sizes, int n_in,
                              void* d_out, int out_size, void* d_ws, size_t ws_size,
                              hipStream_t stream) {
  const float* loc     = (const float*)d_in[0];
  const float* conf    = (const float*)d_in[1];
  const float* binc    = (const float*)d_in[2];
  const float* priors  = (const float*)d_in[3];
  const float* targets = (const float*)d_in[4];
  float* out = (float*)d_out;

  char* ws = (char*)d_ws;
  const size_t S1 = (size_t)NB*NP*4;
  float* ovArr  = (float*)ws;                       // -> reused as ceBin
  int*   btIdx  = (int*)(ws + S1);                  // -> reused as ceMul
  int*   ovr    = (int*)(ws + 2*S1);
  u64*   bpPart = (u64*)(ws + 3*S1);                // NB*NOBJ*PB u64 = 1.23 MB
  char*  p2     = ws + 3*S1 + (size_t)NB*NOBJ*PB*8;
  float* a0P    = (float*)p2;                       // NB*PB = 3072 f32
  float* a1P    = (float*)(p2 + 3072*4);
  float* a2P    = (float*)(p2 + 2*3072*4);
  int*   posCnt = (int*)(p2 + 3*3072*4);
  double* acc   = (double*)(p2 + 4*3072*4);         // 4 f64 (only [3] used)

  float* posOut    = out + 3;
  float* negBinOut = out + 3 + (size_t)NB*NP;
  float* negMulOut = out + 3 + (size_t)2*NB*NP;

  k_init<<<(NB*NP + 255)/256, 256, 0, stream>>>(ovr, acc);
  k_match<<<dim3(PB, NB), 256, 0, stream>>>(priors, targets, ovArr, btIdx, bpPart);
  k_scatter<<<(NB*NOBJ + 255)/256, 256, 0, stream>>>(bpPart, ovArr, ovr);
  k_loss<<<dim3(PB, NB), 256, 0, stream>>>(loc, conf, binc, priors, targets,
      ovArr, btIdx, ovr, ovArr /*ceBin*/, (float*)btIdx /*ceMul*/, posOut,
      a0P, a1P, a2P, posCnt);
  k_rank<<<dim3(NB, 2), 1024, 0, stream>>>(ovArr, (const float*)btIdx, posCnt,
      negBinOut, negMulOut, acc);
  k_final<<<1, 256, 0, stream>>>(a0P, a1P, a2P, posCnt, acc, out);
}

// Round 8
// 217.831 us; speedup vs baseline: 3.6104x; 1.1050x over previous
//
#include <hip/hip_runtime.h>

#define NB 32
#define NP 24564
#define NOBJ 50
#define NC1 20          // NUM_CLASSES - 1
#define WTHRESH 0.5f
#define PB 96           // blocks per batch row = ceil(NP/256)

typedef unsigned long long u64;
typedef unsigned int u32;

// monotone float->uint mapping (works for all floats; our ranked values are >= 0)
__device__ __forceinline__ u32 f2s(float f){
  u32 u = __float_as_uint(f);
  return (u & 0x80000000u) ? ~u : (u | 0x80000000u);
}

__device__ __forceinline__ u64 shfl_down64(u64 x, int off){
  u32 lo = __shfl_down((u32)x, off);
  u32 hi = __shfl_down((u32)(x >> 32), off);
  return (((u64)hi) << 32) | (u64)lo;
}

// ---------------- match: IOU, best-truth per prior, best-prior per truth ----------------
// Each lane owns 4 priors (regs); wave w handles truths t=w,w+4,... over ALL 256 block
// priors -> 4x fewer shuffle-reduce chains. Cross-wave per-prior combine via LDS u64 max.
__global__ __launch_bounds__(256) void k_match(const float* __restrict__ priors,
    const float* __restrict__ targets, float* __restrict__ ovArr,
    int* __restrict__ btIdx, u64* __restrict__ bpPart){
  const int b = blockIdx.y;
  const int blk = blockIdx.x;
  const int tid = threadIdx.x;
  const int lane = tid & 63;
  const int wave = tid >> 6;
  const int base = blk*256;
  __shared__ float tr[NOBJ*5];
  __shared__ u64 wcand[4][256];   // [wave][prior_local] truth-axis candidate
  __shared__ u64 twin[NOBJ];      // per-truth block winner (prior axis)
  if (tid < NOBJ*5) tr[tid] = targets[b*NOBJ*5 + tid];
  // load this lane's 4 priors into registers (point form + area)
  float px1[4], py1[4], px2[4], py2[4], ab[4];
  bool val[4];
  #pragma unroll
  for (int q=0; q<4; q++){
    int p = base + q*64 + lane;
    val[q] = (p < NP);
    float4 pr = val[q] ? reinterpret_cast<const float4*>(priors)[p]
                       : make_float4(0.f,0.f,0.f,0.f);
    px1[q] = pr.x - pr.z*0.5f; py1[q] = pr.y - pr.w*0.5f;
    px2[q] = pr.x + pr.z*0.5f; py2[q] = pr.y + pr.w*0.5f;
    ab[q]  = (px2[q]-px1[q])*(py2[q]-py1[q]);
  }
  __syncthreads();
  u64 cand[4] = {0ull,0ull,0ull,0ull};   // (f2s(iou)<<32)|~t
  for (int t = wave; t < NOBJ; t += 4){
    float tx1=tr[t*5+0], ty1=tr[t*5+1], tx2=tr[t*5+2], ty2=tr[t*5+3];
    float areaA = (tx2-tx1)*(ty2-ty1);
    u64 pk = 0ull;                       // (f2s(iou)<<32)|~j  within lane
    #pragma unroll
    for (int q=0; q<4; q++){
      float w = fmaxf(fminf(tx2,px2[q]) - fmaxf(tx1,px1[q]), 0.f);
      float h = fmaxf(fminf(ty2,py2[q]) - fmaxf(ty1,py1[q]), 0.f);
      float inter = w*h;
      float iou = inter / (areaA + ab[q] - inter);
      if (val[q]){
        u64 s = ((u64)f2s(iou)) << 32;
        u64 ck = s | (u64)(u32)(~(u32)t);
        if (ck > cand[q]) cand[q] = ck;            // equal iou -> smaller t wins
        u64 jk = s | (u64)(u32)(~(u32)(base + q*64 + lane));
        if (jk > pk) pk = jk;                      // equal iou -> smaller j wins
      }
    }
    // wave max-reduce of pk -> block winner for this truth
    #pragma unroll
    for (int off=32; off>0; off>>=1){
      u64 o = shfl_down64(pk, off);
      if (o > pk) pk = o;
    }
    if (lane == 0) twin[t] = pk;
  }
  #pragma unroll
  for (int q=0; q<4; q++) wcand[wave][q*64 + lane] = cand[q];
  __syncthreads();
  { // per-prior cross-wave combine (one thread per prior)
    u64 c0 = wcand[0][tid], c1 = wcand[1][tid];
    u64 c2 = wcand[2][tid], c3 = wcand[3][tid];
    u64 cc = c0 > c1 ? c0 : c1;
    u64 cd = c2 > c3 ? c2 : c3;
    cc = cc > cd ? cc : cd;
    int j = base + tid;
    if (j < NP){
      ovArr[(size_t)b*NP + j] = __uint_as_float((u32)(cc >> 32) & 0x7fffffffu);
      btIdx[(size_t)b*NP + j] = (int)(~(u32)cc);
    }
  }
  if (tid < NOBJ) bpPart[((size_t)b*NOBJ + tid)*PB + blk] = twin[tid];
}

// ---------------- reduce per-block winners -> bpBest[b][t] = winning prior j ----------------
__global__ __launch_bounds__(256) void k_reduce(const u64* __restrict__ bpPart,
    u32* __restrict__ bpBest, double* acc){
  const int b = blockIdx.x;
  const int tid = threadIdx.x;
  if (b == 0 && tid == 0){ acc[0]=0.0; acc[1]=0.0; acc[2]=0.0; acc[3]=0.0; }
  int t = tid >> 2, sub = tid & 3;
  if (t < NOBJ){
    const u64* p = bpPart + ((size_t)b*NOBJ + t)*PB;
    u64 k = 0ull;
    for (int i=sub; i<PB; i+=4){ u64 v = p[i]; k = v > k ? v : k; }
    u64 o = shfl_down64(k, 2); if (o > k) k = o;
    o = shfl_down64(k, 1);     if (o > k) k = o;
    if (sub == 0) bpBest[b*NOBJ + t] = ~(u32)k;    // j index of the winner
  }
}

// ---------------- per-prior losses + pos mask + per-block partial sums ----------------
// ceBinOut aliases ovArr, ceMulOut aliases btIdx (read-before-write per thread).
// Override reconstructed in LDS from bpBest (no ovr array, no init kernel).
__global__ __launch_bounds__(256) void k_loss(
    const float* loc, const float* conf, const float* binc,
    const float* priors, const float* targets, const u32* bpBest,
    const float* ovArr, const int* btIdx,
    float* ceBinOut, float* ceMulOut, float* posOut,
    float* a0P, float* a1P, float* a2P, int* posCnt){
  const int b = blockIdx.y;
  const int j = blockIdx.x*256 + threadIdx.x;
  __shared__ float tr[NOBJ*5];
  __shared__ int ovrL[256];
  __shared__ float s0[4], s1[4], s2s[4];
  __shared__ int scnt[4];
  ovrL[threadIdx.x] = -1;
  if (threadIdx.x < NOBJ*5) tr[threadIdx.x] = targets[b*NOBJ*5 + threadIdx.x];
  __syncthreads();
  if (threadIdx.x < NOBJ){
    int rel = (int)bpBest[b*NOBJ + threadIdx.x] - blockIdx.x*256;
    if (rel >= 0 && rel < 256) atomicMax(&ovrL[rel], threadIdx.x);   // override .max(arange)
  }
  __syncthreads();
  float sl1=0.f, ceB=0.f, ceM=0.f; int isPos=0;
  if (j < NP){
    const size_t idx = (size_t)b*NP + j;
    float4 ld = reinterpret_cast<const float4*>(loc)[idx];
    float2 bc = reinterpret_cast<const float2*>(binc)[idx];
    float4 pr = reinterpret_cast<const float4*>(priors)[j];
    const float4* cp = reinterpret_cast<const float4*>(conf + idx*NC1);
    float4 c0 = cp[0];
    float4 c1 = cp[1];
    float4 c2 = cp[2];
    float4 c3 = cp[3];
    float4 c4 = cp[4];
    int o  = ovrL[threadIdx.x];
    float ov = (o >= 0) ? 2.0f : ovArr[idx];       // .at[best_prior_idx].set(2.0)
    int ti = (o >= 0) ? o : btIdx[idx];
    float tx1=tr[ti*5+0], ty1=tr[ti*5+1], tx2=tr[ti*5+2], ty2=tr[ti*5+3], lab=tr[ti*5+4];
    int conf_t = (ov < WTHRESH) ? 0 : ((int)lab + 1);
    isPos = (conf_t > 0) ? 1 : 0;
    // encode + smooth L1
    float gcx = ((tx1+tx2)*0.5f - pr.x) / (0.1f*pr.z);
    float gcy = ((ty1+ty2)*0.5f - pr.y) / (0.1f*pr.w);
    float gw  = logf((tx2-tx1)/pr.z) / 0.2f;
    float gh  = logf((ty2-ty1)/pr.w) / 0.2f;
    float d0=fabsf(ld.x-gcx), d1=fabsf(ld.y-gcy), d2=fabsf(ld.z-gw), d3=fabsf(ld.w-gh);
    sl1  = (d0<1.f ? 0.5f*d0*d0 : d0-0.5f);
    sl1 += (d1<1.f ? 0.5f*d1*d1 : d1-0.5f);
    sl1 += (d2<1.f ? 0.5f*d2*d2 : d2-0.5f);
    sl1 += (d3<1.f ? 0.5f*d3*d3 : d3-0.5f);
    // binary CE
    float mB = fmaxf(bc.x, bc.y);
    float lseB = logf(expf(bc.x-mB)+expf(bc.y-mB)) + mB;
    ceB = lseB - (isPos ? bc.y : bc.x);
    // multiclass CE over P_logit = [bin0+lse(conf), conf+bin1]
    float mc = fmaxf(fmaxf(fmaxf(c0.x,c0.y),fmaxf(c0.z,c0.w)),
                     fmaxf(fmaxf(c1.x,c1.y),fmaxf(c1.z,c1.w)));
    mc = fmaxf(mc, fmaxf(fmaxf(c2.x,c2.y),fmaxf(c2.z,c2.w)));
    mc = fmaxf(mc, fmaxf(fmaxf(c3.x,c3.y),fmaxf(c3.z,c3.w)));
    mc = fmaxf(mc, fmaxf(fmaxf(c4.x,c4.y),fmaxf(c4.z,c4.w)));
    float se = expf(c0.x-mc); se += expf(c0.y-mc); se += expf(c0.z-mc); se += expf(c0.w-mc);
    se += expf(c1.x-mc); se += expf(c1.y-mc); se += expf(c1.z-mc); se += expf(c1.w-mc);
    se += expf(c2.x-mc); se += expf(c2.y-mc); se += expf(c2.z-mc); se += expf(c2.w-mc);
    se += expf(c3.x-mc); se += expf(c3.y-mc); se += expf(c3.z-mc); se += expf(c3.w-mc);
    se += expf(c4.x-mc); se += expf(c4.y-mc); se += expf(c4.z-mc); se += expf(c4.w-mc);
    float lseC = logf(se) + mc;
    float P0 = bc.x + lseC;
    float m2 = fmaxf(P0, mc + bc.y);
    float s2 = expf(P0 - m2);
    s2 += expf(c0.x + bc.y - m2); s2 += expf(c0.y + bc.y - m2); s2 += expf(c0.z + bc.y - m2); s2 += expf(c0.w + bc.y - m2);
    s2 += expf(c1.x + bc.y - m2); s2 += expf(c1.y + bc.y - m2); s2 += expf(c1.z + bc.y - m2); s2 += expf(c1.w + bc.y - m2);
    s2 += expf(c2.x + bc.y - m2); s2 += expf(c2.y + bc.y - m2); s2 += expf(c2.z + bc.y - m2); s2 += expf(c2.w + bc.y - m2);
    s2 += expf(c3.x + bc.y - m2); s2 += expf(c3.y + bc.y - m2); s2 += expf(c3.z + bc.y - m2); s2 += expf(c3.w + bc.y - m2);
    s2 += expf(c4.x + bc.y - m2); s2 += expf(c4.y + bc.y - m2); s2 += expf(c4.z + bc.y - m2); s2 += expf(c4.w + bc.y - m2);
    float lseM = logf(s2) + m2;
    int sel = conf_t - 1;
    float csel = c0.x;
    csel = (sel== 1) ? c0.y : csel;
    csel = (sel== 2) ? c0.z : csel;
    csel = (sel== 3) ? c0.w : csel;
    csel = (sel== 4) ? c1.x : csel;
    csel = (sel== 5) ? c1.y : csel;
    csel = (sel== 6) ? c1.z : csel;
    csel = (sel== 7) ? c1.w : csel;
    csel = (sel== 8) ? c2.x : csel;
    csel = (sel== 9) ? c2.y : csel;
    csel = (sel==10) ? c2.z : csel;
    csel = (sel==11) ? c2.w : csel;
    csel = (sel==12) ? c3.x : csel;
    csel = (sel==13) ? c3.y : csel;
    csel = (sel==14) ? c3.z : csel;
    csel = (sel==15) ? c3.w : csel;
    csel = (sel==16) ? c4.x : csel;
    csel = (sel==17) ? c4.y : csel;
    csel = (sel==18) ? c4.z : csel;
    csel = (sel==19) ? c4.w : csel;
    float g = (conf_t==0) ? P0 : (csel + bc.y);
    ceM = lseM - g;
    ceBinOut[idx] = isPos ? 0.f : ceB;
    ceMulOut[idx] = isPos ? 0.f : ceM;
    posOut[idx]   = isPos ? 1.f : 0.f;
  }
  // block-level reduction: wave shuffle -> LDS -> single partial write (NO atomics)
  float a0 = isPos ? sl1 : 0.f;
  float a1 = isPos ? ceM : 0.f;
  float a2 = isPos ? ceB : 0.f;
  int cnt = isPos;
  #pragma unroll
  for (int off=32; off>0; off>>=1){
    a0 += __shfl_down(a0, off);
    a1 += __shfl_down(a1, off);
    a2 += __shfl_down(a2, off);
    cnt += __shfl_down(cnt, off);
  }
  if ((threadIdx.x & 63) == 0){
    int w = threadIdx.x >> 6;
    s0[w]=a0; s1[w]=a1; s2s[w]=a2; scnt[w]=cnt;
  }
  __syncthreads();
  if (threadIdx.x == 0){
    int g = b*PB + blockIdx.x;
    a0P[g] = s0[0]+s0[1]+s0[2]+s0[3];
    a1P[g] = s1[0]+s1[1]+s1[2]+s1[3];
    a2P[g] = s2s[0]+s2s[1]+s2s[2]+s2s[3];
    posCnt[g] = scnt[0]+scnt[1]+scnt[2]+scnt[3];
  }
}

// ---------------- exact top-k selection per row (stable-argsort semantics) ----------------
__global__ __launch_bounds__(1024) void k_rank(const float* __restrict__ ceBin,
    const float* __restrict__ ceMul, const int* __restrict__ posCnt,
    float* __restrict__ negBinOut, float* __restrict__ negMulOut, double* acc){
  const int b = blockIdx.x;
  const int which = blockIdx.y;        // 0 = binary loss, 1 = multiclass loss
  const float* arr = (which==0 ? ceBin : ceMul) + (size_t)b*NP;
  float* out = (which==0 ? negBinOut : negMulOut) + (size_t)b*NP;
  const int tid = threadIdx.x;
  __shared__ int s_cnt[PB];
  __shared__ int s_np;
  if (tid < PB) s_cnt[tid] = posCnt[b*PB + tid];
  __syncthreads();
  if (tid == 0){
    int s = 0;
    for (int i=0;i<PB;i++) s += s_cnt[i];
    s_np = s;
  }
  __syncthreads();
  int np = s_np;
  int k = min(3*np, NP-1);
  if (k <= 0){
    for (int i=tid; i<NP; i+=1024) out[i] = 0.f;
    return;
  }
  __shared__ u32 hist[256];
  __shared__ u32 scan[256];
  __shared__ u32 s_pref;
  __shared__ int s_rem;
  if (tid==0){ s_pref = 0u; s_rem = k; }
  if (tid < 256) hist[tid] = 0u;
  __syncthreads();
  for (int r=0; r<4; r++){
    u32 pref = s_pref;
    int sh = 24 - 8*r;
    for (int i=tid; i<NP; i+=1024){
      u32 s = f2s(arr[i]);
      if (r==0 || (s >> (sh+8)) == (pref >> (sh+8)))
        atomicAdd(&hist[(s >> sh) & 255u], 1u);
    }
    __syncthreads();
    if (tid < 256) scan[tid] = hist[tid];
    __syncthreads();
    for (int st=1; st<256; st<<=1){
      u32 add = 0u;
      if (tid < 256 && tid + st < 256) add = scan[tid + st];
      __syncthreads();
      if (tid < 256) scan[tid] += add;
      __syncthreads();
    }
    if (tid < 256){
      u32 rem = (u32)s_rem;
      u32 inclusive = scan[tid];
      u32 above = (tid < 255) ? scan[tid+1] : 0u;
      if (inclusive >= rem && above < rem){   // exactly one bin satisfies this
        s_pref = pref | ((u32)tid << sh);
        s_rem  = (int)(rem - above);
      }
      hist[tid] = 0u;   // reset for next pass
    }
    __syncthreads();
  }
  const u32 kth = s_pref;     // exact k-th largest key
  const int need = s_rem;     // how many of the ties (by smallest index) are selected
  __shared__ int eqCnt;
  __shared__ int eqIdx[2048];
  if (tid==0) eqCnt = 0;
  __syncthreads();
  float sum = 0.f;
  for (int i=tid; i<NP; i+=1024){
    float v = arr[i];
    u32 s = f2s(v);
    float o = 0.f;
    if (s > kth){ o = 1.f; sum += v; }
    else if (s == kth){ int p = atomicAdd(&eqCnt, 1); if (p < 2048) eqIdx[p] = i; }
    out[i] = o;
  }
  __syncthreads();
  int ec = min(eqCnt, 2048);
  for (int e=tid; e<ec; e+=1024){
    int idx = eqIdx[e]; int rank = 0;
    for (int f=0; f<ec; f++) rank += (eqIdx[f] < idx) ? 1 : 0;
    if (rank < need){ out[idx] = 1.f; sum += arr[idx]; }
  }
  if (which==0){
    // block-reduce, ONE atomic per block (32 total across grid)
    __shared__ float s_sum[16];
    #pragma unroll
    for (int off=32; off>0; off>>=1) sum += __shfl_down(sum, off);
    if ((tid & 63) == 0) s_sum[tid >> 6] = sum;
    __syncthreads();
    if (tid == 0){
      float t = 0.f;
      for (int w=0; w<16; w++) t += s_sum[w];
      if (t != 0.f) atomicAdd(&acc[3], (double)t);
    }
  }
}

// ---------------- finalize scalars ----------------
__global__ __launch_bounds__(256) void k_final(const float* __restrict__ a0P,
    const float* __restrict__ a1P, const float* __restrict__ a2P,
    const int* __restrict__ posCnt, const double* __restrict__ acc, float* out){
  const int tid = threadIdx.x;
  double a0=0.0, a1=0.0, a2=0.0; int cnt=0;
  for (int g=tid; g<NB*PB; g+=256){
    a0 += (double)a0P[g];
    a1 += (double)a1P[g];
    a2 += (double)a2P[g];
    cnt += posCnt[g];
  }
  #pragma unroll
  for (int off=32; off>0; off>>=1){
    a0 += __shfl_down(a0, off);
    a1 += __shfl_down(a1, off);
    a2 += __shfl_down(a2, off);
    cnt += __shfl_down(cnt, off);
  }
  __shared__ double sa0[4], sa1[4], sa2[4];
  __shared__ int scn[4];
  if ((tid & 63) == 0){ int w=tid>>6; sa0[w]=a0; sa1[w]=a1; sa2[w]=a2; scn[w]=cnt; }
  __syncthreads();
  if (tid == 0){
    double t0=sa0[0]+sa0[1]+sa0[2]+sa0[3];
    double t1=sa1[0]+sa1[1]+sa1[2]+sa1[3];
    double t2=sa2[0]+sa2[1]+sa2[2]+sa2[3];
    int s = scn[0]+scn[1]+scn[2]+scn[3];
    double N = (double)max(s, 1);
    out[0] = (float)(t0 / N);                 // loss_l / N
    out[1] = (float)(t1 / N);                 // loss_cls / N
    out[2] = (float)((t2 + 3.0*acc[3]) / N);  // loss_b / N  (w_bin[0]=3 on negatives)
  }
}

extern "C" void kernel_launch(void* const* d_in, const int* in_sizes, int n_in,
                              void* d_out, int out_size, void* d_ws, size_t ws_size,
                              hipStream_t stream) {
  const float* loc     = (const float*)d_in[0];
  const float* conf    = (const float*)d_in[1];
  const float* binc    = (const float*)d_in[2];
  const float* priors  = (const float*)d_in[3];
  const float* targets = (const float*)d_in[4];
  float* out = (float*)d_out;

  char* ws = (char*)d_ws;
  const size_t S1 = (size_t)NB*NP*4;
  float* ovArr  = (float*)ws;                       // -> reused as ceBin
  int*   btIdx  = (int*)(ws + S1);                  // -> reused as ceMul
  u64*   bpPart = (u64*)(ws + 2*S1);                // NB*NOBJ*PB u64 = 1.23 MB
  char*  p2     = ws + 2*S1 + (size_t)NB*NOBJ*PB*8;
  u32*   bpBest = (u32*)p2;                         // NB*NOBJ u32
  float* a0P    = (float*)(p2 + NB*NOBJ*4);         // NB*PB = 3072 f32
  float* a1P    = (float*)(p2 + NB*NOBJ*4 + 3072*4);
  float* a2P    = (float*)(p2 + NB*NOBJ*4 + 2*3072*4);
  int*   posCnt = (int*)(p2 + NB*NOBJ*4 + 3*3072*4);
  double* acc   = (double*)(p2 + NB*NOBJ*4 + 4*3072*4); // 4 f64 (only [3] used)

  float* posOut    = out + 3;
  float* negBinOut = out + 3 + (size_t)NB*NP;
  float* negMulOut = out + 3 + (size_t)2*NB*NP;

  k_match<<<dim3(PB, NB), 256, 0, stream>>>(priors, targets, ovArr, btIdx, bpPart);
  k_reduce<<<NB, 256, 0, stream>>>(bpPart, bpBest, acc);
  k_loss<<<dim3(PB, NB), 256, 0, stream>>>(loc, conf, binc, priors, targets, bpBest,
      ovArr, btIdx, ovArr /*ceBin*/, (float*)btIdx /*ceMul*/, posOut,
      a0P, a1P, a2P, posCnt);
  k_rank<<<dim3(NB, 2), 1024, 0, stream>>>(ovArr, (const float*)btIdx, posCnt,
      negBinOut, negMulOut, acc);
  k_final<<<1, 256, 0, stream>>>(a0P, a1P, a2P, posCnt, acc, out);
}

// Round 9
// 209.577 us; speedup vs baseline: 3.7525x; 1.0394x over previous
//
#include <hip/hip_runtime.h>

#define NB 32
#define NP 24564
#define NOBJ 50
#define NC1 20          // NUM_CLASSES - 1
#define WTHRESH 0.5f
#define PB 96           // blocks per batch row = ceil(NP/256)

typedef unsigned long long u64;
typedef unsigned int u32;

// monotone float->uint mapping (works for all floats; our ranked values are >= 0)
__device__ __forceinline__ u32 f2s(float f){
  u32 u = __float_as_uint(f);
  return (u & 0x80000000u) ? ~u : (u | 0x80000000u);
}

__device__ __forceinline__ u64 shfl_down64(u64 x, int off){
  u32 lo = __shfl_down((u32)x, off);
  u32 hi = __shfl_down((u32)(x >> 32), off);
  return (((u64)hi) << 32) | (u64)lo;
}

// ---------------- match: IOU, best-truth per prior, best-prior per truth ----------------
// Each lane owns 4 priors (regs); wave w handles truths t=w,w+4,...
// Inner loop does 32-BIT compare-selects only (u64 packing hoisted out of the pair loop):
//  - truth axis: t ascends per wave -> strict > == first-occurrence (smallest t) per wave;
//    cross-wave tie resolved by packed (key<<32)|~t u64 max in LDS.
//  - prior axis: j ascends over q per lane -> strict > == smallest j per lane;
//    cross-lane tie resolved by packed (key<<32)|~j u64 wave-reduce (once per t).
// iou >= 0 always => f2s(iou) == bits|0x80000000 (1 op).
__global__ __launch_bounds__(256) void k_match(const float* __restrict__ priors,
    const float* __restrict__ targets, float* __restrict__ ovArr,
    int* __restrict__ btIdx, u64* __restrict__ bpPart){
  const int b = blockIdx.y;
  const int blk = blockIdx.x;
  const int tid = threadIdx.x;
  const int lane = tid & 63;
  const int wave = tid >> 6;
  const int base = blk*256;
  __shared__ float tr[NOBJ*5];
  __shared__ u64 wcand[4][256];   // [wave][prior_local] truth-axis candidate
  __shared__ u64 twin[NOBJ];      // per-truth block winner (prior axis)
  if (tid < NOBJ*5) tr[tid] = targets[b*NOBJ*5 + tid];
  // load this lane's 4 priors into registers (point form + area)
  float px1[4], py1[4], px2[4], py2[4], ab[4];
  bool val[4];
  u32 jq[4];
  #pragma unroll
  for (int q=0; q<4; q++){
    int p = base + q*64 + lane;
    jq[q] = (u32)p;
    val[q] = (p < NP);
    float4 pr = val[q] ? reinterpret_cast<const float4*>(priors)[p]
                       : make_float4(0.f,0.f,0.f,0.f);
    px1[q] = pr.x - pr.z*0.5f; py1[q] = pr.y - pr.w*0.5f;
    px2[q] = pr.x + pr.z*0.5f; py2[q] = pr.y + pr.w*0.5f;
    ab[q]  = (px2[q]-px1[q])*(py2[q]-py1[q]);
  }
  __syncthreads();
  u32 ck[4] = {0u,0u,0u,0u};   // best truth-axis key per q
  int ct[4] = {0,0,0,0};       // its truth index
  for (int t = wave; t < NOBJ; t += 4){
    float tx1=tr[t*5+0], ty1=tr[t*5+1], tx2=tr[t*5+2], ty2=tr[t*5+3];
    float areaA = (tx2-tx1)*(ty2-ty1);
    u32 pkk = 0u, pkj = 0u;    // per-truth best (prior axis) within lane
    #pragma unroll
    for (int q=0; q<4; q++){
      float w = fmaxf(fminf(tx2,px2[q]) - fmaxf(tx1,px1[q]), 0.f);
      float h = fmaxf(fminf(ty2,py2[q]) - fmaxf(ty1,py1[q]), 0.f);
      float inter = w*h;
      float iou = inter / (areaA + ab[q] - inter);   // same assoc as before (bit-repro)
      u32 k = __float_as_uint(iou) | 0x80000000u;    // f2s for iou >= 0
      if (val[q]){
        if (k > ck[q]){ ck[q] = k; ct[q] = t; }      // first occurrence: smallest t
        if (k > pkk){ pkk = k; pkj = jq[q]; }        // first occurrence: smallest j
      }
    }
    // pack once per t, wave max-reduce -> block winner for this truth
    u64 pk = (((u64)pkk) << 32) | (u64)(~pkj);
    #pragma unroll
    for (int off=32; off>0; off>>=1){
      u64 o = shfl_down64(pk, off);
      if (o > pk) pk = o;
    }
    if (lane == 0) twin[t] = pk;
  }
  #pragma unroll
  for (int q=0; q<4; q++)
    wcand[wave][q*64 + lane] = (((u64)ck[q]) << 32) | (u64)(u32)(~(u32)ct[q]);
  __syncthreads();
  { // per-prior cross-wave combine (one thread per prior)
    u64 c0 = wcand[0][tid], c1 = wcand[1][tid];
    u64 c2 = wcand[2][tid], c3 = wcand[3][tid];
    u64 cc = c0 > c1 ? c0 : c1;
    u64 cd = c2 > c3 ? c2 : c3;
    cc = cc > cd ? cc : cd;
    int j = base + tid;
    if (j < NP){
      ovArr[(size_t)b*NP + j] = __uint_as_float((u32)(cc >> 32) & 0x7fffffffu);
      btIdx[(size_t)b*NP + j] = (int)(~(u32)cc);
    }
  }
  if (tid < NOBJ) bpPart[((size_t)b*NOBJ + tid)*PB + blk] = twin[tid];
}

// ---------------- reduce per-block winners -> bpBest[b][t] = winning prior j ----------------
__global__ __launch_bounds__(256) void k_reduce(const u64* __restrict__ bpPart,
    u32* __restrict__ bpBest, double* acc){
  const int b = blockIdx.x;
  const int tid = threadIdx.x;
  if (b == 0 && tid == 0){ acc[0]=0.0; acc[1]=0.0; acc[2]=0.0; acc[3]=0.0; }
  int t = tid >> 2, sub = tid & 3;
  if (t < NOBJ){
    const u64* p = bpPart + ((size_t)b*NOBJ + t)*PB;
    u64 k = 0ull;
    for (int i=sub; i<PB; i+=4){ u64 v = p[i]; k = v > k ? v : k; }
    u64 o = shfl_down64(k, 2); if (o > k) k = o;
    o = shfl_down64(k, 1);     if (o > k) k = o;
    if (sub == 0) bpBest[b*NOBJ + t] = ~(u32)k;    // j index of the winner
  }
}

// ---------------- per-prior losses + pos mask + per-block partial sums ----------------
// ceBinOut aliases ovArr, ceMulOut aliases btIdx (read-before-write per thread).
// Override reconstructed in LDS from bpBest (no ovr array, no init kernel).
__global__ __launch_bounds__(256) void k_loss(
    const float* loc, const float* conf, const float* binc,
    const float* priors, const float* targets, const u32* bpBest,
    const float* ovArr, const int* btIdx,
    float* ceBinOut, float* ceMulOut, float* posOut,
    float* a0P, float* a1P, float* a2P, int* posCnt){
  const int b = blockIdx.y;
  const int j = blockIdx.x*256 + threadIdx.x;
  __shared__ float tr[NOBJ*5];
  __shared__ int ovrL[256];
  __shared__ float s0[4], s1[4], s2s[4];
  __shared__ int scnt[4];
  ovrL[threadIdx.x] = -1;
  if (threadIdx.x < NOBJ*5) tr[threadIdx.x] = targets[b*NOBJ*5 + threadIdx.x];
  __syncthreads();
  if (threadIdx.x < NOBJ){
    int rel = (int)bpBest[b*NOBJ + threadIdx.x] - blockIdx.x*256;
    if (rel >= 0 && rel < 256) atomicMax(&ovrL[rel], threadIdx.x);   // override .max(arange)
  }
  __syncthreads();
  float sl1=0.f, ceB=0.f, ceM=0.f; int isPos=0;
  if (j < NP){
    const size_t idx = (size_t)b*NP + j;
    float4 ld = reinterpret_cast<const float4*>(loc)[idx];
    float2 bc = reinterpret_cast<const float2*>(binc)[idx];
    float4 pr = reinterpret_cast<const float4*>(priors)[j];
    const float4* cp = reinterpret_cast<const float4*>(conf + idx*NC1);
    float4 c0 = cp[0];
    float4 c1 = cp[1];
    float4 c2 = cp[2];
    float4 c3 = cp[3];
    float4 c4 = cp[4];
    int o  = ovrL[threadIdx.x];
    float ov = (o >= 0) ? 2.0f : ovArr[idx];       // .at[best_prior_idx].set(2.0)
    int ti = (o >= 0) ? o : btIdx[idx];
    float tx1=tr[ti*5+0], ty1=tr[ti*5+1], tx2=tr[ti*5+2], ty2=tr[ti*5+3], lab=tr[ti*5+4];
    int conf_t = (ov < WTHRESH) ? 0 : ((int)lab + 1);
    isPos = (conf_t > 0) ? 1 : 0;
    // encode + smooth L1
    float gcx = ((tx1+tx2)*0.5f - pr.x) / (0.1f*pr.z);
    float gcy = ((ty1+ty2)*0.5f - pr.y) / (0.1f*pr.w);
    float gw  = logf((tx2-tx1)/pr.z) / 0.2f;
    float gh  = logf((ty2-ty1)/pr.w) / 0.2f;
    float d0=fabsf(ld.x-gcx), d1=fabsf(ld.y-gcy), d2=fabsf(ld.z-gw), d3=fabsf(ld.w-gh);
    sl1  = (d0<1.f ? 0.5f*d0*d0 : d0-0.5f);
    sl1 += (d1<1.f ? 0.5f*d1*d1 : d1-0.5f);
    sl1 += (d2<1.f ? 0.5f*d2*d2 : d2-0.5f);
    sl1 += (d3<1.f ? 0.5f*d3*d3 : d3-0.5f);
    // binary CE
    float mB = fmaxf(bc.x, bc.y);
    float lseB = logf(expf(bc.x-mB)+expf(bc.y-mB)) + mB;
    ceB = lseB - (isPos ? bc.y : bc.x);
    // multiclass CE over P_logit = [bin0+lse(conf), conf+bin1]
    float mc = fmaxf(fmaxf(fmaxf(c0.x,c0.y),fmaxf(c0.z,c0.w)),
                     fmaxf(fmaxf(c1.x,c1.y),fmaxf(c1.z,c1.w)));
    mc = fmaxf(mc, fmaxf(fmaxf(c2.x,c2.y),fmaxf(c2.z,c2.w)));
    mc = fmaxf(mc, fmaxf(fmaxf(c3.x,c3.y),fmaxf(c3.z,c3.w)));
    mc = fmaxf(mc, fmaxf(fmaxf(c4.x,c4.y),fmaxf(c4.z,c4.w)));
    float se = expf(c0.x-mc); se += expf(c0.y-mc); se += expf(c0.z-mc); se += expf(c0.w-mc);
    se += expf(c1.x-mc); se += expf(c1.y-mc); se += expf(c1.z-mc); se += expf(c1.w-mc);
    se += expf(c2.x-mc); se += expf(c2.y-mc); se += expf(c2.z-mc); se += expf(c2.w-mc);
    se += expf(c3.x-mc); se += expf(c3.y-mc); se += expf(c3.z-mc); se += expf(c3.w-mc);
    se += expf(c4.x-mc); se += expf(c4.y-mc); se += expf(c4.z-mc); se += expf(c4.w-mc);
    float lseC = logf(se) + mc;
    float P0 = bc.x + lseC;
    float m2 = fmaxf(P0, mc + bc.y);
    float s2 = expf(P0 - m2);
    s2 += expf(c0.x + bc.y - m2); s2 += expf(c0.y + bc.y - m2); s2 += expf(c0.z + bc.y - m2); s2 += expf(c0.w + bc.y - m2);
    s2 += expf(c1.x + bc.y - m2); s2 += expf(c1.y + bc.y - m2); s2 += expf(c1.z + bc.y - m2); s2 += expf(c1.w + bc.y - m2);
    s2 += expf(c2.x + bc.y - m2); s2 += expf(c2.y + bc.y - m2); s2 += expf(c2.z + bc.y - m2); s2 += expf(c2.w + bc.y - m2);
    s2 += expf(c3.x + bc.y - m2); s2 += expf(c3.y + bc.y - m2); s2 += expf(c3.z + bc.y - m2); s2 += expf(c3.w + bc.y - m2);
    s2 += expf(c4.x + bc.y - m2); s2 += expf(c4.y + bc.y - m2); s2 += expf(c4.z + bc.y - m2); s2 += expf(c4.w + bc.y - m2);
    float lseM = logf(s2) + m2;
    int sel = conf_t - 1;
    float csel = c0.x;
    csel = (sel== 1) ? c0.y : csel;
    csel = (sel== 2) ? c0.z : csel;
    csel = (sel== 3) ? c0.w : csel;
    csel = (sel== 4) ? c1.x : csel;
    csel = (sel== 5) ? c1.y : csel;
    csel = (sel== 6) ? c1.z : csel;
    csel = (sel== 7) ? c1.w : csel;
    csel = (sel== 8) ? c2.x : csel;
    csel = (sel== 9) ? c2.y : csel;
    csel = (sel==10) ? c2.z : csel;
    csel = (sel==11) ? c2.w : csel;
    csel = (sel==12) ? c3.x : csel;
    csel = (sel==13) ? c3.y : csel;
    csel = (sel==14) ? c3.z : csel;
    csel = (sel==15) ? c3.w : csel;
    csel = (sel==16) ? c4.x : csel;
    csel = (sel==17) ? c4.y : csel;
    csel = (sel==18) ? c4.z : csel;
    csel = (sel==19) ? c4.w : csel;
    float g = (conf_t==0) ? P0 : (csel + bc.y);
    ceM = lseM - g;
    ceBinOut[idx] = isPos ? 0.f : ceB;
    ceMulOut[idx] = isPos ? 0.f : ceM;
    posOut[idx]   = isPos ? 1.f : 0.f;
  }
  // block-level reduction: wave shuffle -> LDS -> single partial write (NO atomics)
  float a0 = isPos ? sl1 : 0.f;
  float a1 = isPos ? ceM : 0.f;
  float a2 = isPos ? ceB : 0.f;
  int cnt = isPos;
  #pragma unroll
  for (int off=32; off>0; off>>=1){
    a0 += __shfl_down(a0, off);
    a1 += __shfl_down(a1, off);
    a2 += __shfl_down(a2, off);
    cnt += __shfl_down(cnt, off);
  }
  if ((threadIdx.x & 63) == 0){
    int w = threadIdx.x >> 6;
    s0[w]=a0; s1[w]=a1; s2s[w]=a2; scnt[w]=cnt;
  }
  __syncthreads();
  if (threadIdx.x == 0){
    int g = b*PB + blockIdx.x;
    a0P[g] = s0[0]+s0[1]+s0[2]+s0[3];
    a1P[g] = s1[0]+s1[1]+s1[2]+s1[3];
    a2P[g] = s2s[0]+s2s[1]+s2s[2]+s2s[3];
    posCnt[g] = scnt[0]+scnt[1]+scnt[2]+scnt[3];
  }
}

// ---------------- exact top-k selection per row (stable-argsort semantics) ----------------
__global__ __launch_bounds__(1024) void k_rank(const float* __restrict__ ceBin,
    const float* __restrict__ ceMul, const int* __restrict__ posCnt,
    float* __restrict__ negBinOut, float* __restrict__ negMulOut, double* acc){
  const int b = blockIdx.x;
  const int which = blockIdx.y;        // 0 = binary loss, 1 = multiclass loss
  const float* arr = (which==0 ? ceBin : ceMul) + (size_t)b*NP;
  float* out = (which==0 ? negBinOut : negMulOut) + (size_t)b*NP;
  const int tid = threadIdx.x;
  __shared__ int s_cnt[PB];
  __shared__ int s_np;
  if (tid < PB) s_cnt[tid] = posCnt[b*PB + tid];
  __syncthreads();
  if (tid == 0){
    int s = 0;
    for (int i=0;i<PB;i++) s += s_cnt[i];
    s_np = s;
  }
  __syncthreads();
  int np = s_np;
  int k = min(3*np, NP-1);
  if (k <= 0){
    for (int i=tid; i<NP; i+=1024) out[i] = 0.f;
    return;
  }
  __shared__ u32 hist[256];
  __shared__ u32 scan[256];
  __shared__ u32 s_pref;
  __shared__ int s_rem;
  if (tid==0){ s_pref = 0u; s_rem = k; }
  if (tid < 256) hist[tid] = 0u;
  __syncthreads();
  for (int r=0; r<4; r++){
    u32 pref = s_pref;
    int sh = 24 - 8*r;
    for (int i=tid; i<NP; i+=1024){
      u32 s = f2s(arr[i]);
      if (r==0 || (s >> (sh+8)) == (pref >> (sh+8)))
        atomicAdd(&hist[(s >> sh) & 255u], 1u);
    }
    __syncthreads();
    if (tid < 256) scan[tid] = hist[tid];
    __syncthreads();
    for (int st=1; st<256; st<<=1){
      u32 add = 0u;
      if (tid < 256 && tid + st < 256) add = scan[tid + st];
      __syncthreads();
      if (tid < 256) scan[tid] += add;
      __syncthreads();
    }
    if (tid < 256){
      u32 rem = (u32)s_rem;
      u32 inclusive = scan[tid];
      u32 above = (tid < 255) ? scan[tid+1] : 0u;
      if (inclusive >= rem && above < rem){   // exactly one bin satisfies this
        s_pref = pref | ((u32)tid << sh);
        s_rem  = (int)(rem - above);
      }
      hist[tid] = 0u;   // reset for next pass
    }
    __syncthreads();
  }
  const u32 kth = s_pref;     // exact k-th largest key
  const int need = s_rem;     // how many of the ties (by smallest index) are selected
  __shared__ int eqCnt;
  __shared__ int eqIdx[2048];
  if (tid==0) eqCnt = 0;
  __syncthreads();
  float sum = 0.f;
  for (int i=tid; i<NP; i+=1024){
    float v = arr[i];
    u32 s = f2s(v);
    float o = 0.f;
    if (s > kth){ o = 1.f; sum += v; }
    else if (s == kth){ int p = atomicAdd(&eqCnt, 1); if (p < 2048) eqIdx[p] = i; }
    out[i] = o;
  }
  __syncthreads();
  int ec = min(eqCnt, 2048);
  for (int e=tid; e<ec; e+=1024){
    int idx = eqIdx[e]; int rank = 0;
    for (int f=0; f<ec; f++) rank += (eqIdx[f] < idx) ? 1 : 0;
    if (rank < need){ out[idx] = 1.f; sum += arr[idx]; }
  }
  if (which==0){
    // block-reduce, ONE atomic per block (32 total across grid)
    __shared__ float s_sum[16];
    #pragma unroll
    for (int off=32; off>0; off>>=1) sum += __shfl_down(sum, off);
    if ((tid & 63) == 0) s_sum[tid >> 6] = sum;
    __syncthreads();
    if (tid == 0){
      float t = 0.f;
      for (int w=0; w<16; w++) t += s_sum[w];
      if (t != 0.f) atomicAdd(&acc[3], (double)t);
    }
  }
}

// ---------------- finalize scalars ----------------
__global__ __launch_bounds__(256) void k_final(const float* __restrict__ a0P,
    const float* __restrict__ a1P, const float* __restrict__ a2P,
    const int* __restrict__ posCnt, const double* __restrict__ acc, float* out){
  const int tid = threadIdx.x;
  double a0=0.0, a1=0.0, a2=0.0; int cnt=0;
  for (int g=tid; g<NB*PB; g+=256){
    a0 += (double)a0P[g];
    a1 += (double)a1P[g];
    a2 += (double)a2P[g];
    cnt += posCnt[g];
  }
  #pragma unroll
  for (int off=32; off>0; off>>=1){
    a0 += __shfl_down(a0, off);
    a1 += __shfl_down(a1, off);
    a2 += __shfl_down(a2, off);
    cnt += __shfl_down(cnt, off);
  }
  __shared__ double sa0[4], sa1[4], sa2[4];
  __shared__ int scn[4];
  if ((tid & 63) == 0){ int w=tid>>6; sa0[w]=a0; sa1[w]=a1; sa2[w]=a2; scn[w]=cnt; }
  __syncthreads();
  if (tid == 0){
    double t0=sa0[0]+sa0[1]+sa0[2]+sa0[3];
    double t1=sa1[0]+sa1[1]+sa1[2]+sa1[3];
    double t2=sa2[0]+sa2[1]+sa2[2]+sa2[3];
    int s = scn[0]+scn[1]+scn[2]+scn[3];
    double N = (double)max(s, 1);
    out[0] = (float)(t0 / N);                 // loss_l / N
    out[1] = (float)(t1 / N);                 // loss_cls / N
    out[2] = (float)((t2 + 3.0*acc[3]) / N);  // loss_b / N  (w_bin[0]=3 on negatives)
  }
}

extern "C" void kernel_launch(void* const* d_in, const int* in_sizes, int n_in,
                              void* d_out, int out_size, void* d_ws, size_t ws_size,
                              hipStream_t stream) {
  const float* loc     = (const float*)d_in[0];
  const float* conf    = (const float*)d_in[1];
  const float* binc    = (const float*)d_in[2];
  const float* priors  = (const float*)d_in[3];
  const float* targets = (const float*)d_in[4];
  float* out = (float*)d_out;

  char* ws = (char*)d_ws;
  const size_t S1 = (size_t)NB*NP*4;
  float* ovArr  = (float*)ws;                       // -> reused as ceBin
  int*   btIdx  = (int*)(ws + S1);                  // -> reused as ceMul
  u64*   bpPart = (u64*)(ws + 2*S1);                // NB*NOBJ*PB u64 = 1.23 MB
  char*  p2     = ws + 2*S1 + (size_t)NB*NOBJ*PB*8;
  u32*   bpBest = (u32*)p2;                         // NB*NOBJ u32
  float* a0P    = (float*)(p2 + NB*NOBJ*4);         // NB*PB = 3072 f32
  float* a1P    = (float*)(p2 + NB*NOBJ*4 + 3072*4);
  float* a2P    = (float*)(p2 + NB*NOBJ*4 + 2*3072*4);
  int*   posCnt = (int*)(p2 + NB*NOBJ*4 + 3*3072*4);
  double* acc   = (double*)(p2 + NB*NOBJ*4 + 4*3072*4); // 4 f64 (only [3] used)

  float* posOut    = out + 3;
  float* negBinOut = out + 3 + (size_t)NB*NP;
  float* negMulOut = out + 3 + (size_t)2*NB*NP;

  k_match<<<dim3(PB, NB), 256, 0, stream>>>(priors, targets, ovArr, btIdx, bpPart);
  k_reduce<<<NB, 256, 0, stream>>>(bpPart, bpBest, acc);
  k_loss<<<dim3(PB, NB), 256, 0, stream>>>(loc, conf, binc, priors, targets, bpBest,
      ovArr, btIdx, ovArr /*ceBin*/, (float*)btIdx /*ceMul*/, posOut,
      a0P, a1P, a2P, posCnt);
  k_rank<<<dim3(NB, 2), 1024, 0, stream>>>(ovArr, (const float*)btIdx, posCnt,
      negBinOut, negMulOut, acc);
  k_final<<<1, 256, 0, stream>>>(a0P, a1P, a2P, posCnt, acc, out);
}

// Round 11
// 196.248 us; speedup vs baseline: 4.0074x; 1.0679x over previous
//
#include <hip/hip_runtime.h>

#define NB 32
#define NP 24564
#define NOBJ 50
#define NC1 20          // NUM_CLASSES - 1
#define WTHRESH 0.5f
#define PB 96           // blocks per batch row = ceil(NP/256)
#define NSLOT 24        // ceil(NP/1024) per-thread elements in k_rank

typedef unsigned long long u64;
typedef unsigned int u32;

// monotone float->uint mapping (works for all floats; our ranked values are >= 0)
__device__ __forceinline__ u32 f2s(float f){
  u32 u = __float_as_uint(f);
  return (u & 0x80000000u) ? ~u : (u | 0x80000000u);
}

__device__ __forceinline__ u64 shfl_down64(u64 x, int off){
  u32 lo = __shfl_down((u32)x, off);
  u32 hi = __shfl_down((u32)(x >> 32), off);
  return (((u64)hi) << 32) | (u64)lo;
}

// ---------------- match: IOU, best-truth per prior, best-prior per truth ----------------
// Each lane owns 4 priors (regs); wave w handles truths t=w,w+4,...
// Inner loop does 32-BIT compare-selects only (u64 packing hoisted out of the pair loop).
__global__ __launch_bounds__(256) void k_match(const float* __restrict__ priors,
    const float* __restrict__ targets, float* __restrict__ ovArr,
    int* __restrict__ btIdx, u64* __restrict__ bpPart){
  const int b = blockIdx.y;
  const int blk = blockIdx.x;
  const int tid = threadIdx.x;
  const int lane = tid & 63;
  const int wave = tid >> 6;
  const int base = blk*256;
  __shared__ float tr[NOBJ*5];
  __shared__ u64 wcand[4][256];   // [wave][prior_local] truth-axis candidate
  __shared__ u64 twin[NOBJ];      // per-truth block winner (prior axis)
  if (tid < NOBJ*5) tr[tid] = targets[b*NOBJ*5 + tid];
  float px1[4], py1[4], px2[4], py2[4], ab[4];
  bool val[4];
  u32 jq[4];
  #pragma unroll
  for (int q=0; q<4; q++){
    int p = base + q*64 + lane;
    jq[q] = (u32)p;
    val[q] = (p < NP);
    float4 pr = val[q] ? reinterpret_cast<const float4*>(priors)[p]
                       : make_float4(0.f,0.f,0.f,0.f);
    px1[q] = pr.x - pr.z*0.5f; py1[q] = pr.y - pr.w*0.5f;
    px2[q] = pr.x + pr.z*0.5f; py2[q] = pr.y + pr.w*0.5f;
    ab[q]  = (px2[q]-px1[q])*(py2[q]-py1[q]);
  }
  __syncthreads();
  u32 ck[4] = {0u,0u,0u,0u};   // best truth-axis key per q
  int ct[4] = {0,0,0,0};       // its truth index
  for (int t = wave; t < NOBJ; t += 4){
    float tx1=tr[t*5+0], ty1=tr[t*5+1], tx2=tr[t*5+2], ty2=tr[t*5+3];
    float areaA = (tx2-tx1)*(ty2-ty1);
    u32 pkk = 0u, pkj = 0u;    // per-truth best (prior axis) within lane
    #pragma unroll
    for (int q=0; q<4; q++){
      float w = fmaxf(fminf(tx2,px2[q]) - fmaxf(tx1,px1[q]), 0.f);
      float h = fmaxf(fminf(ty2,py2[q]) - fmaxf(ty1,py1[q]), 0.f);
      float inter = w*h;
      float iou = inter / (areaA + ab[q] - inter);   // same assoc as before (bit-repro)
      u32 k = __float_as_uint(iou) | 0x80000000u;    // f2s for iou >= 0
      if (val[q]){
        if (k > ck[q]){ ck[q] = k; ct[q] = t; }      // first occurrence: smallest t
        if (k > pkk){ pkk = k; pkj = jq[q]; }        // first occurrence: smallest j
      }
    }
    u64 pk = (((u64)pkk) << 32) | (u64)(~pkj);
    #pragma unroll
    for (int off=32; off>0; off>>=1){
      u64 o = shfl_down64(pk, off);
      if (o > pk) pk = o;
    }
    if (lane == 0) twin[t] = pk;
  }
  #pragma unroll
  for (int q=0; q<4; q++)
    wcand[wave][q*64 + lane] = (((u64)ck[q]) << 32) | (u64)(u32)(~(u32)ct[q]);
  __syncthreads();
  { // per-prior cross-wave combine (one thread per prior)
    u64 c0 = wcand[0][tid], c1 = wcand[1][tid];
    u64 c2 = wcand[2][tid], c3 = wcand[3][tid];
    u64 cc = c0 > c1 ? c0 : c1;
    u64 cd = c2 > c3 ? c2 : c3;
    cc = cc > cd ? cc : cd;
    int j = base + tid;
    if (j < NP){
      ovArr[(size_t)b*NP + j] = __uint_as_float((u32)(cc >> 32) & 0x7fffffffu);
      btIdx[(size_t)b*NP + j] = (int)(~(u32)cc);
    }
  }
  if (tid < NOBJ) bpPart[((size_t)b*NOBJ + tid)*PB + blk] = twin[tid];
}

// ---------------- reduce per-block winners -> bpBest[b][t] = winning prior j ----------------
__global__ __launch_bounds__(256) void k_reduce(const u64* __restrict__ bpPart,
    u32* __restrict__ bpBest, double* acc){
  const int b = blockIdx.x;
  const int tid = threadIdx.x;
  if (b == 0 && tid == 0){ acc[0]=0.0; acc[1]=0.0; acc[2]=0.0; acc[3]=0.0; }
  int t = tid >> 2, sub = tid & 3;
  if (t < NOBJ){
    const u64* p = bpPart + ((size_t)b*NOBJ + t)*PB;
    u64 k = 0ull;
    for (int i=sub; i<PB; i+=4){ u64 v = p[i]; k = v > k ? v : k; }
    u64 o = shfl_down64(k, 2); if (o > k) k = o;
    o = shfl_down64(k, 1);     if (o > k) k = o;
    if (sub == 0) bpBest[b*NOBJ + t] = ~(u32)k;    // j index of the winner
  }
}

// ---------------- per-prior losses + pos mask + per-block partial sums ----------------
__global__ __launch_bounds__(256) void k_loss(
    const float* loc, const float* conf, const float* binc,
    const float* priors, const float* targets, const u32* bpBest,
    const float* ovArr, const int* btIdx,
    float* ceBinOut, float* ceMulOut, float* posOut,
    float* a0P, float* a1P, float* a2P, int* posCnt){
  const int b = blockIdx.y;
  const int j = blockIdx.x*256 + threadIdx.x;
  __shared__ float tr[NOBJ*5];
  __shared__ int ovrL[256];
  __shared__ float s0[4], s1[4], s2s[4];
  __shared__ int scnt[4];
  ovrL[threadIdx.x] = -1;
  if (threadIdx.x < NOBJ*5) tr[threadIdx.x] = targets[b*NOBJ*5 + threadIdx.x];
  __syncthreads();
  if (threadIdx.x < NOBJ){
    int rel = (int)bpBest[b*NOBJ + threadIdx.x] - blockIdx.x*256;
    if (rel >= 0 && rel < 256) atomicMax(&ovrL[rel], threadIdx.x);   // override .max(arange)
  }
  __syncthreads();
  float sl1=0.f, ceB=0.f, ceM=0.f; int isPos=0;
  if (j < NP){
    const size_t idx = (size_t)b*NP + j;
    float4 ld = reinterpret_cast<const float4*>(loc)[idx];
    float2 bc = reinterpret_cast<const float2*>(binc)[idx];
    float4 pr = reinterpret_cast<const float4*>(priors)[j];
    const float4* cp = reinterpret_cast<const float4*>(conf + idx*NC1);
    float4 c0 = cp[0];
    float4 c1 = cp[1];
    float4 c2 = cp[2];
    float4 c3 = cp[3];
    float4 c4 = cp[4];
    int o  = ovrL[threadIdx.x];
    float ov = (o >= 0) ? 2.0f : ovArr[idx];       // .at[best_prior_idx].set(2.0)
    int ti = (o >= 0) ? o : btIdx[idx];
    float tx1=tr[ti*5+0], ty1=tr[ti*5+1], tx2=tr[ti*5+2], ty2=tr[ti*5+3], lab=tr[ti*5+4];
    int conf_t = (ov < WTHRESH) ? 0 : ((int)lab + 1);
    isPos = (conf_t > 0) ? 1 : 0;
    // encode + smooth L1
    float gcx = ((tx1+tx2)*0.5f - pr.x) / (0.1f*pr.z);
    float gcy = ((ty1+ty2)*0.5f - pr.y) / (0.1f*pr.w);
    float gw  = logf((tx2-tx1)/pr.z) / 0.2f;
    float gh  = logf((ty2-ty1)/pr.w) / 0.2f;
    float d0=fabsf(ld.x-gcx), d1=fabsf(ld.y-gcy), d2=fabsf(ld.z-gw), d3=fabsf(ld.w-gh);
    sl1  = (d0<1.f ? 0.5f*d0*d0 : d0-0.5f);
    sl1 += (d1<1.f ? 0.5f*d1*d1 : d1-0.5f);
    sl1 += (d2<1.f ? 0.5f*d2*d2 : d2-0.5f);
    sl1 += (d3<1.f ? 0.5f*d3*d3 : d3-0.5f);
    // binary CE
    float mB = fmaxf(bc.x, bc.y);
    float lseB = logf(expf(bc.x-mB)+expf(bc.y-mB)) + mB;
    ceB = lseB - (isPos ? bc.y : bc.x);
    // multiclass CE over P_logit = [bin0+lse(conf), conf+bin1]
    float mc = fmaxf(fmaxf(fmaxf(c0.x,c0.y),fmaxf(c0.z,c0.w)),
                     fmaxf(fmaxf(c1.x,c1.y),fmaxf(c1.z,c1.w)));
    mc = fmaxf(mc, fmaxf(fmaxf(c2.x,c2.y),fmaxf(c2.z,c2.w)));
    mc = fmaxf(mc, fmaxf(fmaxf(c3.x,c3.y),fmaxf(c3.z,c3.w)));
    mc = fmaxf(mc, fmaxf(fmaxf(c4.x,c4.y),fmaxf(c4.z,c4.w)));
    float se = expf(c0.x-mc); se += expf(c0.y-mc); se += expf(c0.z-mc); se += expf(c0.w-mc);
    se += expf(c1.x-mc); se += expf(c1.y-mc); se += expf(c1.z-mc); se += expf(c1.w-mc);
    se += expf(c2.x-mc); se += expf(c2.y-mc); se += expf(c2.z-mc); se += expf(c2.w-mc);
    se += expf(c3.x-mc); se += expf(c3.y-mc); se += expf(c3.z-mc); se += expf(c3.w-mc);
    se += expf(c4.x-mc); se += expf(c4.y-mc); se += expf(c4.z-mc); se += expf(c4.w-mc);
    float lseC = logf(se) + mc;
    float P0 = bc.x + lseC;
    float m2 = fmaxf(P0, mc + bc.y);
    float s2 = expf(P0 - m2);
    s2 += expf(c0.x + bc.y - m2); s2 += expf(c0.y + bc.y - m2); s2 += expf(c0.z + bc.y - m2); s2 += expf(c0.w + bc.y - m2);
    s2 += expf(c1.x + bc.y - m2); s2 += expf(c1.y + bc.y - m2); s2 += expf(c1.z + bc.y - m2); s2 += expf(c1.w + bc.y - m2);
    s2 += expf(c2.x + bc.y - m2); s2 += expf(c2.y + bc.y - m2); s2 += expf(c2.z + bc.y - m2); s2 += expf(c2.w + bc.y - m2);
    s2 += expf(c3.x + bc.y - m2); s2 += expf(c3.y + bc.y - m2); s2 += expf(c3.z + bc.y - m2); s2 += expf(c3.w + bc.y - m2);
    s2 += expf(c4.x + bc.y - m2); s2 += expf(c4.y + bc.y - m2); s2 += expf(c4.z + bc.y - m2); s2 += expf(c4.w + bc.y - m2);
    float lseM = logf(s2) + m2;
    int sel = conf_t - 1;
    float csel = c0.x;
    csel = (sel== 1) ? c0.y : csel;
    csel = (sel== 2) ? c0.z : csel;
    csel = (sel== 3) ? c0.w : csel;
    csel = (sel== 4) ? c1.x : csel;
    csel = (sel== 5) ? c1.y : csel;
    csel = (sel== 6) ? c1.z : csel;
    csel = (sel== 7) ? c1.w : csel;
    csel = (sel== 8) ? c2.x : csel;
    csel = (sel== 9) ? c2.y : csel;
    csel = (sel==10) ? c2.z : csel;
    csel = (sel==11) ? c2.w : csel;
    csel = (sel==12) ? c3.x : csel;
    csel = (sel==13) ? c3.y : csel;
    csel = (sel==14) ? c3.z : csel;
    csel = (sel==15) ? c3.w : csel;
    csel = (sel==16) ? c4.x : csel;
    csel = (sel==17) ? c4.y : csel;
    csel = (sel==18) ? c4.z : csel;
    csel = (sel==19) ? c4.w : csel;
    float g = (conf_t==0) ? P0 : (csel + bc.y);
    ceM = lseM - g;
    ceBinOut[idx] = isPos ? 0.f : ceB;
    ceMulOut[idx] = isPos ? 0.f : ceM;
    posOut[idx]   = isPos ? 1.f : 0.f;
  }
  float a0 = isPos ? sl1 : 0.f;
  float a1 = isPos ? ceM : 0.f;
  float a2 = isPos ? ceB : 0.f;
  int cnt = isPos;
  #pragma unroll
  for (int off=32; off>0; off>>=1){
    a0 += __shfl_down(a0, off);
    a1 += __shfl_down(a1, off);
    a2 += __shfl_down(a2, off);
    cnt += __shfl_down(cnt, off);
  }
  if ((threadIdx.x & 63) == 0){
    int w = threadIdx.x >> 6;
    s0[w]=a0; s1[w]=a1; s2s[w]=a2; scnt[w]=cnt;
  }
  __syncthreads();
  if (threadIdx.x == 0){
    int g = b*PB + blockIdx.x;
    a0P[g] = s0[0]+s0[1]+s0[2]+s0[3];
    a1P[g] = s1[0]+s1[1]+s1[2]+s1[3];
    a2P[g] = s2s[0]+s2s[1]+s2s[2]+s2s[3];
    posCnt[g] = scnt[0]+scnt[1]+scnt[2]+scnt[3];
  }
}

// ---------------- exact top-k selection per row (stable-argsort semantics) ----------------
// Keys register-resident: ONE global read pass instead of five.
// Phantom slots (i>=NP) hold key 0 (top bit clear); real keys all have top bit set and
// rem <= NP-1 <= #real-keys, so bin 0 can never be chosen -> phantoms harmless.
__global__ __launch_bounds__(1024) void k_rank(const float* __restrict__ ceBin,
    const float* __restrict__ ceMul, const int* __restrict__ posCnt,
    float* __restrict__ negBinOut, float* __restrict__ negMulOut, double* acc){
  const int b = blockIdx.x;
  const int which = blockIdx.y;        // 0 = binary loss, 1 = multiclass loss
  const float* arr = (which==0 ? ceBin : ceMul) + (size_t)b*NP;
  float* out = (which==0 ? negBinOut : negMulOut) + (size_t)b*NP;
  const int tid = threadIdx.x;
  __shared__ int s_cnt[PB];
  __shared__ int s_np;
  if (tid < PB) s_cnt[tid] = posCnt[b*PB + tid];
  __syncthreads();
  if (tid == 0){
    int s = 0;
    for (int i=0;i<PB;i++) s += s_cnt[i];
    s_np = s;
  }
  // load this thread's keys into registers (static indexing only -> stays in VGPRs)
  u32 key[NSLOT];
  #pragma unroll
  for (int s=0; s<NSLOT; s++){
    int i = tid + s*1024;
    key[s] = (i < NP) ? f2s(arr[i]) : 0u;
  }
  __syncthreads();
  int np = s_np;
  int k = min(3*np, NP-1);
  if (k <= 0){
    for (int i=tid; i<NP; i+=1024) out[i] = 0.f;
    return;
  }
  __shared__ u32 hist[256];
  __shared__ u32 scan[256];
  __shared__ u32 s_pref;
  __shared__ int s_rem;
  if (tid==0){ s_pref = 0u; s_rem = k; }
  if (tid < 256) hist[tid] = 0u;
  __syncthreads();
  for (int r=0; r<4; r++){
    u32 pref = s_pref;
    int sh = 24 - 8*r;
    #pragma unroll
    for (int s=0; s<NSLOT; s++){
      u32 kk = key[s];
      if (r==0 || (kk >> (sh+8)) == (pref >> (sh+8)))
        atomicAdd(&hist[(kk >> sh) & 255u], 1u);
    }
    __syncthreads();
    if (tid < 256) scan[tid] = hist[tid];
    __syncthreads();
    for (int st=1; st<256; st<<=1){
      u32 add = 0u;
      if (tid < 256 && tid + st < 256) add = scan[tid + st];
      __syncthreads();
      if (tid < 256) scan[tid] += add;
      __syncthreads();
    }
    if (tid < 256){
      u32 rem = (u32)s_rem;
      u32 inclusive = scan[tid];
      u32 above = (tid < 255) ? scan[tid+1] : 0u;
      if (inclusive >= rem && above < rem){   // exactly one bin satisfies this
        s_pref = pref | ((u32)tid << sh);
        s_rem  = (int)(rem - above);
      }
      hist[tid] = 0u;   // reset for next pass
    }
    __syncthreads();
  }
  const u32 kth = s_pref;     // exact k-th largest key
  const int need = s_rem;     // how many of the ties (by smallest index) are selected
  __shared__ int eqCnt;
  __shared__ int eqIdx[2048];
  if (tid==0) eqCnt = 0;
  __syncthreads();
  float sum = 0.f;
  #pragma unroll
  for (int s=0; s<NSLOT; s++){
    int i = tid + s*1024;
    u32 kk = key[s];
    if (i < NP){
      float o = 0.f;
      if (kk > kth){ o = 1.f; sum += __uint_as_float(kk & 0x7fffffffu); }
      else if (kk == kth){ int p = atomicAdd(&eqCnt, 1); if (p < 2048) eqIdx[p] = i; }
      out[i] = o;
    }
  }
  __syncthreads();
  int ec = min(eqCnt, 2048);
  for (int e=tid; e<ec; e+=1024){
    int idx = eqIdx[e]; int rank = 0;
    for (int f=0; f<ec; f++) rank += (eqIdx[f] < idx) ? 1 : 0;
    if (rank < need){ out[idx] = 1.f; sum += arr[idx]; }
  }
  if (which==0){
    // block-reduce, ONE atomic per block (32 total across grid)
    __shared__ float s_sum[16];
    #pragma unroll
    for (int off=32; off>0; off>>=1) sum += __shfl_down(sum, off);
    if ((tid & 63) == 0) s_sum[tid >> 6] = sum;
    __syncthreads();
    if (tid == 0){
      float t = 0.f;
      for (int w=0; w<16; w++) t += s_sum[w];
      if (t != 0.f) atomicAdd(&acc[3], (double)t);
    }
  }
}

// ---------------- finalize scalars ----------------
__global__ __launch_bounds__(256) void k_final(const float* __restrict__ a0P,
    const float* __restrict__ a1P, const float* __restrict__ a2P,
    const int* __restrict__ posCnt, const double* __restrict__ acc, float* out){
  const int tid = threadIdx.x;
  double a0=0.0, a1=0.0, a2=0.0; int cnt=0;
  for (int g=tid; g<NB*PB; g+=256){
    a0 += (double)a0P[g];
    a1 += (double)a1P[g];
    a2 += (double)a2P[g];
    cnt += posCnt[g];
  }
  #pragma unroll
  for (int off=32; off>0; off>>=1){
    a0 += __shfl_down(a0, off);
    a1 += __shfl_down(a1, off);
    a2 += __shfl_down(a2, off);
    cnt += __shfl_down(cnt, off);
  }
  __shared__ double sa0[4], sa1[4], sa2[4];
  __shared__ int scn[4];
  if ((tid & 63) == 0){ int w=tid>>6; sa0[w]=a0; sa1[w]=a1; sa2[w]=a2; scn[w]=cnt; }
  __syncthreads();
  if (tid == 0){
    double t0=sa0[0]+sa0[1]+sa0[2]+sa0[3];
    double t1=sa1[0]+sa1[1]+sa1[2]+sa1[3];
    double t2=sa2[0]+sa2[1]+sa2[2]+sa2[3];
    int s = scn[0]+scn[1]+scn[2]+scn[3];
    double N = (double)max(s, 1);
    out[0] = (float)(t0 / N);                 // loss_l / N
    out[1] = (float)(t1 / N);                 // loss_cls / N
    out[2] = (float)((t2 + 3.0*acc[3]) / N);  // loss_b / N  (w_bin[0]=3 on negatives)
  }
}

extern "C" void kernel_launch(void* const* d_in, const int* in_sizes, int n_in,
                              void* d_out, int out_size, void* d_ws, size_t ws_size,
                              hipStream_t stream) {
  const float* loc     = (const float*)d_in[0];
  const float* conf    = (const float*)d_in[1];
  const float* binc    = (const float*)d_in[2];
  const float* priors  = (const float*)d_in[3];
  const float* targets = (const float*)d_in[4];
  float* out = (float*)d_out;

  char* ws = (char*)d_ws;
  const size_t S1 = (size_t)NB*NP*4;
  float* ovArr  = (float*)ws;                       // -> reused as ceBin
  int*   btIdx  = (int*)(ws + S1);                  // -> reused as ceMul
  u64*   bpPart = (u64*)(ws + 2*S1);                // NB*NOBJ*PB u64 = 1.23 MB
  char*  p2     = ws + 2*S1 + (size_t)NB*NOBJ*PB*8;
  u32*   bpBest = (u32*)p2;                         // NB*NOBJ u32
  float* a0P    = (float*)(p2 + NB*NOBJ*4);         // NB*PB = 3072 f32
  float* a1P    = (float*)(p2 + NB*NOBJ*4 + 3072*4);
  float* a2P    = (float*)(p2 + NB*NOBJ*4 + 2*3072*4);
  int*   posCnt = (int*)(p2 + NB*NOBJ*4 + 3*3072*4);
  double* acc   = (double*)(p2 + NB*NOBJ*4 + 4*3072*4); // 4 f64 (only [3] used)

  float* posOut    = out + 3;
  float* negBinOut = out + 3 + (size_t)NB*NP;
  float* negMulOut = out + 3 + (size_t)2*NB*NP;

  k_match<<<dim3(PB, NB), 256, 0, stream>>>(priors, targets, ovArr, btIdx, bpPart);
  k_reduce<<<NB, 256, 0, stream>>>(bpPart, bpBest, acc);
  k_loss<<<dim3(PB, NB), 256, 0, stream>>>(loc, conf, binc, priors, targets, bpBest,
      ovArr, btIdx, ovArr /*ceBin*/, (float*)btIdx /*ceMul*/, posOut,
      a0P, a1P, a2P, posCnt);
  k_rank<<<dim3(NB, 2), 1024, 0, stream>>>(ovArr, (const float*)btIdx, posCnt,
      negBinOut, negMulOut, acc);
  k_final<<<1, 256, 0, stream>>>(a0P, a1P, a2P, posCnt, acc, out);
}